// Round 3
// baseline (1372.779 us; speedup 1.0000x reference)
//
#include <hip/hip_runtime.h>
#include <hip/hip_bf16.h>
#include <cstddef>

constexpr int cB = 8, cN = 8192, cM = 2048, cK = 16, cC = 128, cH = 64, cO = 256, cCH = 192;
constexpr int NPTS = cB * cM;        // 16384
constexpr float cEPS = 1e-5f;

// ---- workspace layout (float offsets) ----
constexpr size_t ACC_BN1 = 0, ACC_BN2 = 128, ACC_STEM = 256, ACC_X1 = 768, ACC_X2 = 1280, ACC_FIN = 1792;
constexpr size_t OFF_SFT = 8192;                                  // s_feats transposed [B,N,C] f32
constexpr size_t OFF_TST = OFF_SFT + (size_t)cB * cN * cC;        // stem post-ELU [NPTS,256] f32; later h2T bf16 [NPTS,64,16]
constexpr size_t OFF_Y1  = OFF_TST + (size_t)NPTS * 256;          // y1 post-ELU  [NPTS,256] f32
constexpr size_t OFF_Y2  = OFF_Y1  + (size_t)NPTS * 256;          // y2 post-ELU  [NPTS,256] f32
constexpr size_t OFF_DW  = OFF_Y2  + (size_t)NPTS * 256;          // dw matrix    [NPTS,192] f32
constexpr size_t WS_FLOATS = OFF_DW + (size_t)NPTS * cCH;

__device__ __forceinline__ float eluf(float x) { return x > 0.f ? x : expm1f(x); }

// wave-internal LDS visibility: wave64 is lockstep; DS ops counted by lgkmcnt.
#define WAVE_SYNC() do { asm volatile("s_waitcnt lgkmcnt(0)" ::: "memory"); \
                         __builtin_amdgcn_sched_barrier(0); } while (0)

// ---- transpose s_feats [B,C,N] -> [B,N,C] ----
__global__ __launch_bounds__(256) void k_tr(const float* __restrict__ sf, float* __restrict__ sfT) {
    __shared__ float tile[32][33];
    int b = blockIdx.z, n0 = blockIdx.x * 32, c0 = blockIdx.y * 32;
    int tx = threadIdx.x, ty = threadIdx.y;
    #pragma unroll
    for (int j = 0; j < 32; j += 8)
        tile[ty + j][tx] = sf[((size_t)b * cC + (c0 + ty + j)) * cN + n0 + tx];
    __syncthreads();
    #pragma unroll
    for (int j = 0; j < 32; j += 8)
        sfT[((size_t)b * cN + (n0 + ty + j)) * cC + c0 + tx] = tile[tx][ty + j];
}

// ---- kA: BN1 (h1) stats + stem conv (store post-ELU [pt][o]) + stem stats ----
// wave-per-4-points, barrier-free inner; weights amortized over 4 pts.
__global__ __launch_bounds__(256) void kA(const float* __restrict__ qp, const float* __restrict__ sp,
        const float* __restrict__ f1w, const float* __restrict__ f1b,
        const float* __restrict__ stw, const float* __restrict__ stb,
        const int* __restrict__ nidx, float* __restrict__ ws) {
    __shared__ float sw[256 * 49];     // [o][j] pad 49 -> 2-way free
    __shared__ float al4[4][192];      // per wave: [p][c*16+k]
    __shared__ float red[640];         // 0..127 BN1, 128..639 stem
    int t = threadIdx.x, lane = t & 63, w = t >> 6;
    for (int l = t; l < 256 * 48; l += 256) sw[(l / 48) * 49 + (l % 48)] = stw[l];
    for (int l = t; l < 640; l += 256) red[l] = 0.f;
    float w0 = f1w[lane*3], w1 = f1w[lane*3+1], w2 = f1w[lane*3+2], fb = f1b[lane];
    float sb[4];
    #pragma unroll
    for (int q = 0; q < 4; q++) sb[q] = stb[lane + 64*q];
    __syncthreads();
    int pt0 = blockIdx.x * 16 + w * 4;
    // gather aligned coords for 4 pts: lane -> (p = lane>>4, k = lane&15), 3 channels
    {
        int p = lane >> 4, k = lane & 15;
        int pt = pt0 + p, b = pt >> 11, m = pt & (cM - 1);
        int id = nidx[(size_t)pt * cK + k];
        #pragma unroll
        for (int c = 0; c < 3; c++)
            al4[w][p*48 + c*16 + k] = sp[((size_t)b*3 + c)*cN + id] - qp[((size_t)b*3 + c)*cM + m];
    }
    WAVE_SYNC();
    // h1 stats: channel c = lane
    float ps1 = 0, pss1 = 0;
    #pragma unroll
    for (int p = 0; p < 4; p++)
        #pragma unroll
        for (int k = 0; k < 16; k++) {
            float a0 = al4[w][p*48 + k], a1 = al4[w][p*48 + 16 + k], a2 = al4[w][p*48 + 32 + k];
            float e = eluf(fb + w0*a0 + w1*a1 + w2*a2);
            ps1 += e; pss1 += e*e;
        }
    // stem: outputs o = lane + 64q, 4 points batched
    float acc[4][4];
    #pragma unroll
    for (int q = 0; q < 4; q++)
        #pragma unroll
        for (int p = 0; p < 4; p++) acc[q][p] = sb[q];
    #pragma unroll
    for (int j4 = 0; j4 < 12; j4++) {
        float4 a[4];
        #pragma unroll
        for (int p = 0; p < 4; p++) a[p] = *(const float4*)&al4[w][p*48 + j4*4];
        #pragma unroll
        for (int q = 0; q < 4; q++) {
            int o = lane + 64*q;
            float s0 = sw[o*49 + j4*4], s1 = sw[o*49 + j4*4+1], s2 = sw[o*49 + j4*4+2], s3 = sw[o*49 + j4*4+3];
            #pragma unroll
            for (int p = 0; p < 4; p++)
                acc[q][p] += s0*a[p].x + s1*a[p].y + s2*a[p].z + s3*a[p].w;
        }
    }
    float ps2[4] = {0,0,0,0}, pss2[4] = {0,0,0,0};
    #pragma unroll
    for (int q = 0; q < 4; q++)
        #pragma unroll
        for (int p = 0; p < 4; p++) {
            float e = eluf(acc[q][p]);
            ps2[q] += e; pss2[q] += e*e;
            ws[OFF_TST + (size_t)(pt0 + p)*256 + lane + 64*q] = e;
        }
    atomicAdd(&red[lane], ps1); atomicAdd(&red[64 + lane], pss1);
    #pragma unroll
    for (int q = 0; q < 4; q++) {
        atomicAdd(&red[128 + lane + 64*q], ps2[q]);
        atomicAdd(&red[384 + lane + 64*q], pss2[q]);
    }
    __syncthreads();
    if (t < 64) { atomicAdd(&ws[ACC_BN1 + t], red[t]); atomicAdd(&ws[ACC_BN1 + 64 + t], red[64 + t]); }
    atomicAdd(&ws[ACC_STEM + t], red[128 + t]); atomicAdd(&ws[ACC_STEM + 256 + t], red[384 + t]);
}

// ---- kE: stem(BN inline) -> grouped conv x1 -> store y1 post-ELU [pt][o] + x1 stats ----
__global__ __launch_bounds__(256) void kE(const float* __restrict__ x1w, const float* __restrict__ x1b,
        const float* __restrict__ stg, const float* __restrict__ stbe, float* __restrict__ ws) {
    __shared__ float xw[256 * 17];
    __shared__ float ts[4][4][256];
    __shared__ float red[512];
    int t = threadIdx.x, lane = t & 63, w = t >> 6;
    for (int l = t; l < 4096; l += 256) xw[(l >> 4)*17 + (l & 15)] = x1w[l];
    for (int l = t; l < 512; l += 256) red[l] = 0.f;
    float sscl[4], sshf[4];
    #pragma unroll
    for (int i = 0; i < 4; i++) {
        int ch = lane*4 + i;
        float mn = ws[ACC_STEM + ch] * (1.f/16384.f);
        float vr = ws[ACC_STEM + 256 + ch] * (1.f/16384.f) - mn*mn;
        float s = stg[ch] * rsqrtf(vr + cEPS);
        sscl[i] = s; sshf[i] = stbe[ch] - mn*s;
    }
    float xb[4];
    #pragma unroll
    for (int q = 0; q < 4; q++) xb[q] = x1b[lane + 64*q];
    __syncthreads();
    int pt0 = blockIdx.x * 16 + w * 4;
    #pragma unroll
    for (int p = 0; p < 4; p++) {
        float4 v = *(const float4*)&ws[OFF_TST + (size_t)(pt0 + p)*256 + lane*4];
        v.x = sscl[0]*v.x + sshf[0]; v.y = sscl[1]*v.y + sshf[1];
        v.z = sscl[2]*v.z + sshf[2]; v.w = sscl[3]*v.w + sshf[3];
        *(float4*)&ts[w][p][lane*4] = v;
    }
    WAVE_SYNC();
    float ps[4] = {0,0,0,0}, pss[4] = {0,0,0,0};
    #pragma unroll
    for (int q = 0; q < 4; q++) {
        int o = lane + 64*q, g = o >> 4;
        float accp[4] = {xb[q], xb[q], xb[q], xb[q]};
        #pragma unroll
        for (int j4 = 0; j4 < 4; j4++) {
            float s0 = xw[o*17 + j4*4], s1 = xw[o*17 + j4*4+1], s2 = xw[o*17 + j4*4+2], s3 = xw[o*17 + j4*4+3];
            #pragma unroll
            for (int p = 0; p < 4; p++) {
                float4 a = *(const float4*)&ts[w][p][g*16 + j4*4];
                accp[p] += s0*a.x + s1*a.y + s2*a.z + s3*a.w;
            }
        }
        #pragma unroll
        for (int p = 0; p < 4; p++) {
            float e = eluf(accp[p]);
            ps[q] += e; pss[q] += e*e;
            ws[OFF_Y1 + (size_t)(pt0 + p)*256 + o] = e;
        }
    }
    #pragma unroll
    for (int q = 0; q < 4; q++) {
        atomicAdd(&red[lane + 64*q], ps[q]);
        atomicAdd(&red[256 + lane + 64*q], pss[q]);
    }
    __syncthreads();
    atomicAdd(&ws[ACC_X1 + t], red[t]); atomicAdd(&ws[ACC_X1 + 256 + t], red[256 + t]);
}

// ---- kG: y1(BN_x1 inline, transposed stage) -> grouped conv x2 -> y2 [pt][o] + x2 stats ----
__global__ __launch_bounds__(256) void kG(const float* __restrict__ x2w, const float* __restrict__ x2b,
        const float* __restrict__ x1g, const float* __restrict__ x1be, float* __restrict__ ws) {
    __shared__ float xw[256 * 17];
    __shared__ float ts[4][4][256];    // stores S[g*16+j] = y1bn[j*16+g]
    __shared__ float red[512];
    int t = threadIdx.x, lane = t & 63, w = t >> 6;
    for (int l = t; l < 4096; l += 256) xw[(l >> 4)*17 + (l & 15)] = x2w[l];
    for (int l = t; l < 512; l += 256) red[l] = 0.f;
    float sscl[4], sshf[4];
    #pragma unroll
    for (int i = 0; i < 4; i++) {
        int ch = lane*4 + i;
        float mn = ws[ACC_X1 + ch] * (1.f/16384.f);
        float vr = ws[ACC_X1 + 256 + ch] * (1.f/16384.f) - mn*mn;
        float s = x1g[ch] * rsqrtf(vr + cEPS);
        sscl[i] = s; sshf[i] = x1be[ch] - mn*s;
    }
    float xb[4];
    #pragma unroll
    for (int q = 0; q < 4; q++) xb[q] = x2b[lane + 64*q];
    __syncthreads();
    int pt0 = blockIdx.x * 16 + w * 4;
    #pragma unroll
    for (int p = 0; p < 4; p++) {
        float4 v = *(const float4*)&ws[OFF_Y1 + (size_t)(pt0 + p)*256 + lane*4];
        float vv[4] = { sscl[0]*v.x + sshf[0], sscl[1]*v.y + sshf[1],
                        sscl[2]*v.z + sshf[2], sscl[3]*v.w + sshf[3] };
        #pragma unroll
        for (int i = 0; i < 4; i++) {
            int ch = lane*4 + i;
            ts[w][p][((ch & 15) << 4) | (ch >> 4)] = vv[i];
        }
    }
    WAVE_SYNC();
    float ps[4] = {0,0,0,0}, pss[4] = {0,0,0,0};
    #pragma unroll
    for (int q = 0; q < 4; q++) {
        int o = lane + 64*q, g = o >> 4;
        float accp[4] = {xb[q], xb[q], xb[q], xb[q]};
        #pragma unroll
        for (int j4 = 0; j4 < 4; j4++) {
            float s0 = xw[o*17 + j4*4], s1 = xw[o*17 + j4*4+1], s2 = xw[o*17 + j4*4+2], s3 = xw[o*17 + j4*4+3];
            #pragma unroll
            for (int p = 0; p < 4; p++) {
                float4 a = *(const float4*)&ts[w][p][g*16 + j4*4];
                accp[p] += s0*a.x + s1*a.y + s2*a.z + s3*a.w;
            }
        }
        #pragma unroll
        for (int p = 0; p < 4; p++) {
            float e = eluf(accp[p]);
            ps[q] += e; pss[q] += e*e;
            ws[OFF_Y2 + (size_t)(pt0 + p)*256 + o] = e;
        }
    }
    #pragma unroll
    for (int q = 0; q < 4; q++) {
        atomicAdd(&red[lane + 64*q], ps[q]);
        atomicAdd(&red[256 + lane + 64*q], pss[q]);
    }
    __syncthreads();
    atomicAdd(&ws[ACC_X2 + t], red[t]); atomicAdd(&ws[ACC_X2 + 256 + t], red[256 + t]);
}

// ---- kC: h1(BN1 inline) -> h2 post-ELU -> store bf16 TRANSPOSED [pt][o][k] + BN2 stats ----
__global__ __launch_bounds__(256) void kC(const float* __restrict__ qp, const float* __restrict__ sp,
        const float* __restrict__ f1w, const float* __restrict__ f1b,
        const float* __restrict__ f2w, const float* __restrict__ f2b,
        const float* __restrict__ f1g, const float* __restrict__ f1be,
        const int* __restrict__ nidx, float* __restrict__ ws) {
    __shared__ float f2t[4096];        // [c][o] transposed -> conflict-free reads
    __shared__ float h1s[4][1024];     // per wave: [k*64+c]
    __shared__ float al4[4][48];
    __shared__ float red[128];
    __hip_bfloat16* h2b = (__hip_bfloat16*)(ws + OFF_TST);
    int t = threadIdx.x, lane = t & 63, w = t >> 6;
    for (int l = t; l < 4096; l += 256) f2t[l] = f2w[(size_t)(l & 63)*64 + (l >> 6)];
    if (t < 128) red[t] = 0.f;
    float w0 = f1w[lane*3], w1 = f1w[lane*3+1], w2 = f1w[lane*3+2], fb = f1b[lane];
    float s1, sh1;
    {
        float mn = ws[ACC_BN1 + lane] * (1.f/262144.f);
        float vr = ws[ACC_BN1 + 64 + lane] * (1.f/262144.f) - mn*mn;
        s1 = f1g[lane] * rsqrtf(vr + cEPS);
        sh1 = f1be[lane] - mn*s1;
    }
    float f2bv = f2b[lane];
    __syncthreads();
    int pt0 = blockIdx.x * 16 + w * 4;
    float ps = 0, pss = 0;
    for (int p = 0; p < 4; p++) {
        int pt = pt0 + p, b = pt >> 11, m = pt & (cM - 1);
        if (lane < 48) {
            int c = lane >> 4, k = lane & 15;
            int id = nidx[(size_t)pt * cK + k];
            al4[w][c*16 + k] = sp[((size_t)b*3 + c)*cN + id] - qp[((size_t)b*3 + c)*cM + m];
        }
        WAVE_SYNC();
        #pragma unroll
        for (int k = 0; k < 16; k++) {
            float a0 = al4[w][k], a1 = al4[w][16 + k], a2 = al4[w][32 + k];
            h1s[w][k*64 + lane] = s1 * eluf(fb + w0*a0 + w1*a1 + w2*a2) + sh1;
        }
        WAVE_SYNC();
        float acc[16];
        #pragma unroll
        for (int k = 0; k < 16; k++) acc[k] = f2bv;
        #pragma unroll
        for (int c0 = 0; c0 < 64; c0 += 4) {
            float g0 = f2t[(c0+0)*64 + lane], g1 = f2t[(c0+1)*64 + lane];
            float g2 = f2t[(c0+2)*64 + lane], g3 = f2t[(c0+3)*64 + lane];
            #pragma unroll
            for (int k = 0; k < 16; k++) {
                float4 hv = *(const float4*)&h1s[w][k*64 + c0];
                acc[k] += g0*hv.x + g1*hv.y + g2*hv.z + g3*hv.w;
            }
        }
        __hip_bfloat16 hb[16];
        #pragma unroll
        for (int k = 0; k < 16; k++) {
            float e = eluf(acc[k]);
            ps += e; pss += e*e;
            hb[k] = __float2bfloat16(e);
        }
        __hip_bfloat16* dst = h2b + (size_t)pt*1024 + lane*16;
        *(uint4*)dst = *(const uint4*)&hb[0];
        *(uint4*)(dst + 8) = *(const uint4*)&hb[8];
        WAVE_SYNC();   // al4/h1s reused next p
    }
    atomicAdd(&red[lane], ps); atomicAdd(&red[64 + lane], pss);
    __syncthreads();
    if (t < 64) { atomicAdd(&ws[ACC_BN2 + t], red[t]); atomicAdd(&ws[ACC_BN2 + 64 + t], red[64 + t]); }
}

// ---- kI: wave-per-point gather+qf+depthwise. nf channels in registers. ----
__global__ __launch_bounds__(256) void kI(const float* __restrict__ dww,
        const float* __restrict__ f2g, const float* __restrict__ f2be,
        const float* __restrict__ x2g, const float* __restrict__ x2be,
        const int* __restrict__ nidx, float* __restrict__ ws) {
    __shared__ float dws[192 * 17];    // [c][l] pad 17
    __shared__ float xs[4][256];       // per wave x matrix [k*16+l]
    const __hip_bfloat16* h2b = (const __hip_bfloat16*)(ws + OFF_TST);
    int t = threadIdx.x, lane = t & 63, w = t >> 6;
    for (int l = t; l < 3072; l += 256) dws[(l >> 4)*17 + (l & 15)] = dww[l];
    float sx[4], shx[4];
    #pragma unroll
    for (int i = 0; i < 4; i++) {
        int ch = lane*4 + i;
        float mn = ws[ACC_X2 + ch] * (1.f/16384.f);
        float vr = ws[ACC_X2 + 256 + ch] * (1.f/16384.f) - mn*mn;
        float s = x2g[ch] * rsqrtf(vr + cEPS);
        sx[i] = s; shx[i] = x2be[ch] - mn*s;
    }
    float s2, sh2;
    {
        float mn = ws[ACC_BN2 + lane] * (1.f/262144.f);
        float vr = ws[ACC_BN2 + 64 + lane] * (1.f/262144.f) - mn*mn;
        s2 = f2g[lane] * rsqrtf(vr + cEPS);
        sh2 = f2be[lane] - mn*s2;
    }
    __syncthreads();
    int pt0 = blockIdx.x * 8 + w * 2;
    for (int p = 0; p < 2; p++) {
        int pt = pt0 + p, b = pt >> 11;
        const int4* ip = (const int4*)(nidx + (size_t)pt * cK);
        int4 iA = ip[0], iB = ip[1], iC2 = ip[2], iD = ip[3];
        int idxv[16] = {iA.x, iA.y, iA.z, iA.w, iB.x, iB.y, iB.z, iB.w,
                        iC2.x, iC2.y, iC2.z, iC2.w, iD.x, iD.y, iD.z, iD.w};
        // gather s_feats rows: channels lane, lane+64 in regs
        float nfa[16], nfb[16];
        #pragma unroll
        for (int k = 0; k < 16; k++) {
            const float* rp = ws + OFF_SFT + ((size_t)b*cN + idxv[k]) * cC;
            nfa[k] = rp[lane];
            nfb[k] = rp[lane + 64];
        }
        // h2 (third channel block) with BN2 affine -> regs
        float nfh[16];
        {
            __hip_bfloat16 hb[16];
            const __hip_bfloat16* src = h2b + (size_t)pt*1024 + lane*16;
            *(uint4*)&hb[0] = *(const uint4*)src;
            *(uint4*)&hb[8] = *(const uint4*)(src + 8);
            #pragma unroll
            for (int k = 0; k < 16; k++) nfh[k] = s2 * __bfloat162float(hb[k]) + sh2;
        }
        // x matrix into per-wave LDS
        {
            float4 v = *(const float4*)&ws[OFF_Y2 + (size_t)pt*256 + lane*4];
            v.x = sx[0]*v.x + shx[0]; v.y = sx[1]*v.y + shx[1];
            v.z = sx[2]*v.z + shx[2]; v.w = sx[3]*v.w + shx[3];
            *(float4*)&xs[w][lane*4] = v;
        }
        WAVE_SYNC();
        // pass 1: channel lane+128 (h2) — data arrives earliest
        float qc[16];
        #pragma unroll
        for (int l = 0; l < 16; l++) qc[l] = 0.f;
        #pragma unroll
        for (int k = 0; k < 16; k++) {
            float4 x0 = *(const float4*)&xs[w][k*16 + 0];
            float4 x1 = *(const float4*)&xs[w][k*16 + 4];
            float4 x2v = *(const float4*)&xs[w][k*16 + 8];
            float4 x3 = *(const float4*)&xs[w][k*16 + 12];
            float nh = nfh[k];
            qc[0] += nh*x0.x; qc[1] += nh*x0.y; qc[2]  += nh*x0.z; qc[3]  += nh*x0.w;
            qc[4] += nh*x1.x; qc[5] += nh*x1.y; qc[6]  += nh*x1.z; qc[7]  += nh*x1.w;
            qc[8] += nh*x2v.x; qc[9] += nh*x2v.y; qc[10] += nh*x2v.z; qc[11] += nh*x2v.w;
            qc[12] += nh*x3.x; qc[13] += nh*x3.y; qc[14] += nh*x3.z; qc[15] += nh*x3.w;
        }
        float dc = 0;
        #pragma unroll
        for (int l = 0; l < 16; l++) dc += qc[l] * dws[(lane + 128)*17 + l];
        // pass 2: channels lane, lane+64 (gathered)
        float qa[16], qb[16];
        #pragma unroll
        for (int l = 0; l < 16; l++) { qa[l] = 0.f; qb[l] = 0.f; }
        #pragma unroll
        for (int k = 0; k < 16; k++) {
            float4 x0 = *(const float4*)&xs[w][k*16 + 0];
            float4 x1 = *(const float4*)&xs[w][k*16 + 4];
            float4 x2v = *(const float4*)&xs[w][k*16 + 8];
            float4 x3 = *(const float4*)&xs[w][k*16 + 12];
            float na = nfa[k], nb = nfb[k];
            qa[0] += na*x0.x; qa[1] += na*x0.y; qa[2]  += na*x0.z; qa[3]  += na*x0.w;
            qa[4] += na*x1.x; qa[5] += na*x1.y; qa[6]  += na*x1.z; qa[7]  += na*x1.w;
            qa[8] += na*x2v.x; qa[9] += na*x2v.y; qa[10] += na*x2v.z; qa[11] += na*x2v.w;
            qa[12] += na*x3.x; qa[13] += na*x3.y; qa[14] += na*x3.z; qa[15] += na*x3.w;
            qb[0] += nb*x0.x; qb[1] += nb*x0.y; qb[2]  += nb*x0.z; qb[3]  += nb*x0.w;
            qb[4] += nb*x1.x; qb[5] += nb*x1.y; qb[6]  += nb*x1.z; qb[7]  += nb*x1.w;
            qb[8] += nb*x2v.x; qb[9] += nb*x2v.y; qb[10] += nb*x2v.z; qb[11] += nb*x2v.w;
            qb[12] += nb*x3.x; qb[13] += nb*x3.y; qb[14] += nb*x3.z; qb[15] += nb*x3.w;
        }
        float da = 0, db = 0;
        #pragma unroll
        for (int l = 0; l < 16; l++) {
            da += qa[l] * dws[lane*17 + l];
            db += qb[l] * dws[(lane + 64)*17 + l];
        }
        float* op = ws + OFF_DW + (size_t)pt * cCH;
        op[lane] = da; op[lane + 64] = db; op[lane + 128] = dc;
        WAVE_SYNC();   // xs reused next p
    }
}

// ---- kJ: [16384x192]x[192x256] GEMM + bias + ELU + final stats ----
__global__ __launch_bounds__(256) void kJ(const float* __restrict__ pww, const float* __restrict__ pwb,
                                          float* __restrict__ ws, float* __restrict__ out) {
    __shared__ float As[16][65];
    __shared__ float Bs[16][65];
    int t = threadIdx.x;
    int tx = t & 15, ty = t >> 4;
    int p0 = blockIdx.x * 64, o0 = blockIdx.y * 64;
    float acc[4][4];
    #pragma unroll
    for (int i = 0; i < 4; i++)
        #pragma unroll
        for (int j = 0; j < 4; j++) acc[i][j] = 0.f;
    int la = t * 4;
    int apl = la >> 4, akl = la & 15;
    for (int kt = 0; kt < 12; kt++) {
        float4 av = *(const float4*)&ws[OFF_DW + (size_t)(p0 + apl)*cCH + kt*16 + akl];
        float4 bv = *(const float4*)&pww[(size_t)(o0 + apl)*cCH + kt*16 + akl];
        As[akl][apl] = av.x; As[akl+1][apl] = av.y; As[akl+2][apl] = av.z; As[akl+3][apl] = av.w;
        Bs[akl][apl] = bv.x; Bs[akl+1][apl] = bv.y; Bs[akl+2][apl] = bv.z; Bs[akl+3][apl] = bv.w;
        __syncthreads();
        #pragma unroll
        for (int kk = 0; kk < 16; kk++) {
            float a0 = As[kk][tx*4], a1 = As[kk][tx*4+1], a2 = As[kk][tx*4+2], a3 = As[kk][tx*4+3];
            float b0 = Bs[kk][ty*4], b1 = Bs[kk][ty*4+1], b2 = Bs[kk][ty*4+2], b3 = Bs[kk][ty*4+3];
            acc[0][0]+=a0*b0; acc[0][1]+=a0*b1; acc[0][2]+=a0*b2; acc[0][3]+=a0*b3;
            acc[1][0]+=a1*b0; acc[1][1]+=a1*b1; acc[1][2]+=a1*b2; acc[1][3]+=a1*b3;
            acc[2][0]+=a2*b0; acc[2][1]+=a2*b1; acc[2][2]+=a2*b2; acc[2][3]+=a2*b3;
            acc[3][0]+=a3*b0; acc[3][1]+=a3*b1; acc[3][2]+=a3*b2; acc[3][3]+=a3*b3;
        }
        __syncthreads();
    }
    int b = p0 >> 11, mb = (p0 & (cM - 1)) + tx*4;
    #pragma unroll
    for (int j = 0; j < 4; j++) {
        int oo = o0 + ty*4 + j;
        float pb = pwb[oo];
        float e0 = eluf(acc[0][j] + pb), e1 = eluf(acc[1][j] + pb);
        float e2 = eluf(acc[2][j] + pb), e3 = eluf(acc[3][j] + pb);
        float sum = e0+e1+e2+e3, ssq = e0*e0+e1*e1+e2*e2+e3*e3;
        #pragma unroll
        for (int off = 1; off < 16; off <<= 1) { sum += __shfl_xor(sum, off); ssq += __shfl_xor(ssq, off); }
        if (tx == 0) { atomicAdd(&ws[ACC_FIN + oo], sum); atomicAdd(&ws[ACC_FIN + 256 + oo], ssq); }
        float4 st = make_float4(e0, e1, e2, e3);
        *(float4*)&out[((size_t)b*cO + oo)*cM + mb] = st;
    }
}

// ---- kK: final BN affine in-place (inline finalize) ----
__global__ __launch_bounds__(256) void kK(float* __restrict__ out, const float* __restrict__ ws,
        const float* __restrict__ sepg, const float* __restrict__ sepbe) {
    int i = blockIdx.x * 256 + threadIdx.x;
    if (i < (cB*cO*cM) / 4) {
        int o = (i >> 9) & 255;
        float mn = ws[ACC_FIN + o] * (1.f/16384.f);
        float vr = ws[ACC_FIN + 256 + o] * (1.f/16384.f) - mn*mn;
        float s = sepg[o] * rsqrtf(vr + cEPS);
        float sh = sepbe[o] - mn*s;
        float4 v = ((float4*)out)[i];
        v.x = s*v.x + sh; v.y = s*v.y + sh; v.z = s*v.z + sh; v.w = s*v.w + sh;
        ((float4*)out)[i] = v;
    }
}

extern "C" void kernel_launch(void* const* d_in, const int* in_sizes, int n_in,
                              void* d_out, int out_size, void* d_ws, size_t ws_size,
                              hipStream_t stream) {
    const float* qp   = (const float*)d_in[0];
    const float* sp   = (const float*)d_in[1];
    const float* sf   = (const float*)d_in[2];
    const float* f1w  = (const float*)d_in[3];
    const float* f1b  = (const float*)d_in[4];
    const float* f1g  = (const float*)d_in[5];
    const float* f1be = (const float*)d_in[6];
    const float* f2w  = (const float*)d_in[7];
    const float* f2b  = (const float*)d_in[8];
    const float* f2g  = (const float*)d_in[9];
    const float* f2be = (const float*)d_in[10];
    const float* stw  = (const float*)d_in[11];
    const float* stb  = (const float*)d_in[12];
    const float* stg  = (const float*)d_in[13];
    const float* stbe = (const float*)d_in[14];
    const float* x1w  = (const float*)d_in[15];
    const float* x1b  = (const float*)d_in[16];
    const float* x1g  = (const float*)d_in[17];
    const float* x1be = (const float*)d_in[18];
    const float* x2w  = (const float*)d_in[19];
    const float* x2b  = (const float*)d_in[20];
    const float* x2g  = (const float*)d_in[21];
    const float* x2be = (const float*)d_in[22];
    const float* dww  = (const float*)d_in[23];
    const float* pww  = (const float*)d_in[24];
    const float* pwb  = (const float*)d_in[25];
    const float* sepg = (const float*)d_in[26];
    const float* sepbe= (const float*)d_in[27];
    const int*   nidx = (const int*)d_in[28];
    float* ws  = (float*)d_ws;
    float* out = (float*)d_out;
    if (ws_size < WS_FLOATS * sizeof(float)) return;

    hipMemsetAsync(d_ws, 0, 2304 * sizeof(float), stream);  // zero stat accumulators
    k_tr<<<dim3(cN/32, cC/32, cB), dim3(32, 8), 0, stream>>>(sf, ws + OFF_SFT);
    kA<<<NPTS/16, 256, 0, stream>>>(qp, sp, f1w, f1b, stw, stb, nidx, ws);
    kE<<<NPTS/16, 256, 0, stream>>>(x1w, x1b, stg, stbe, ws);
    kG<<<NPTS/16, 256, 0, stream>>>(x2w, x2b, x1g, x1be, ws);
    kC<<<NPTS/16, 256, 0, stream>>>(qp, sp, f1w, f1b, f2w, f2b, f1g, f1be, nidx, ws);
    kI<<<NPTS/8,  256, 0, stream>>>(dww, f2g, f2be, x2g, x2be, nidx, ws);
    kJ<<<dim3(NPTS/64, cO/64), 256, 0, stream>>>(pww, pwb, ws, out);
    kK<<<(cB*cO*cM/4 + 255)/256, 256, 0, stream>>>(out, ws, sepg, sepbe);
}

// Round 4
// 495.235 us; speedup vs baseline: 2.7720x; 2.7720x over previous
//
#include <hip/hip_runtime.h>
#include <hip/hip_bf16.h>
#include <cstddef>
#include <cstdint>

constexpr int cB = 8, cN = 8192, cM = 2048, cK = 16, cC = 128, cH = 64, cO = 256, cCH = 192;
constexpr int NPTS = cB * cM;        // 16384
constexpr float cEPS = 1e-5f;

// ---- workspace layout (float offsets) ----
constexpr size_t ACC_BN1 = 0, ACC_BN2 = 128, ACC_STEM = 256, ACC_X1 = 768, ACC_X2 = 1280, ACC_FIN = 1792;
constexpr size_t OFF_SFT = 8192;                                  // s_feats transposed [B,N,C] f32
constexpr size_t OFF_TST = OFF_SFT + (size_t)cB * cN * cC;        // stem post-ELU [NPTS,256] f32; later h2T bf16 [NPTS,64,16]
constexpr size_t OFF_Y1  = OFF_TST + (size_t)NPTS * 256;          // y1 post-ELU  [NPTS,256] f32
constexpr size_t OFF_Y2  = OFF_Y1  + (size_t)NPTS * 256;          // y2 post-ELU  [NPTS,256] f32
constexpr size_t OFF_DW  = OFF_Y2  + (size_t)NPTS * 256;          // dw matrix    [NPTS,192] f32
constexpr size_t WS_FLOATS = OFF_DW + (size_t)NPTS * cCH;

__device__ __forceinline__ float eluf(float x) { return x > 0.f ? x : expm1f(x); }

// pack two f32 -> two bf16 (RNE) in one u32: low = a, high = b. Pure reg ops, no arrays.
__device__ __forceinline__ uint32_t pk2bf(float a, float b) {
    uint32_t ua = __float_as_uint(a); ua += 0x7FFFu + ((ua >> 16) & 1u);
    uint32_t ub = __float_as_uint(b); ub += 0x7FFFu + ((ub >> 16) & 1u);
    return (ua >> 16) | (ub & 0xFFFF0000u);
}
__device__ __forceinline__ float bf_lo(uint32_t u) { return __uint_as_float(u << 16); }
__device__ __forceinline__ float bf_hi(uint32_t u) { return __uint_as_float(u & 0xFFFF0000u); }

// wave-internal LDS visibility: wave64 is lockstep; DS ops counted by lgkmcnt.
#define WAVE_SYNC() do { asm volatile("s_waitcnt lgkmcnt(0)" ::: "memory"); \
                         __builtin_amdgcn_sched_barrier(0); } while (0)

// ---- transpose s_feats [B,C,N] -> [B,N,C] ----
__global__ __launch_bounds__(256) void k_tr(const float* __restrict__ sf, float* __restrict__ sfT) {
    __shared__ float tile[32][33];
    int b = blockIdx.z, n0 = blockIdx.x * 32, c0 = blockIdx.y * 32;
    int tx = threadIdx.x, ty = threadIdx.y;
    #pragma unroll
    for (int j = 0; j < 32; j += 8)
        tile[ty + j][tx] = sf[((size_t)b * cC + (c0 + ty + j)) * cN + n0 + tx];
    __syncthreads();
    #pragma unroll
    for (int j = 0; j < 32; j += 8)
        sfT[((size_t)b * cN + (n0 + ty + j)) * cC + c0 + tx] = tile[tx][ty + j];
}

// ---- kA: BN1 (h1) stats + stem conv (store post-ELU [pt][o]) + stem stats ----
__global__ __launch_bounds__(256) void kA(const float* __restrict__ qp, const float* __restrict__ sp,
        const float* __restrict__ f1w, const float* __restrict__ f1b,
        const float* __restrict__ stw, const float* __restrict__ stb,
        const int* __restrict__ nidx, float* __restrict__ ws) {
    __shared__ float sw[256 * 49];     // [o][j] pad 49 -> 2-way free
    __shared__ float al4[4][192];      // per wave: [p][c*16+k]
    __shared__ float red[640];         // 0..127 BN1, 128..639 stem
    int t = threadIdx.x, lane = t & 63, w = t >> 6;
    for (int l = t; l < 256 * 48; l += 256) sw[(l / 48) * 49 + (l % 48)] = stw[l];
    for (int l = t; l < 640; l += 256) red[l] = 0.f;
    float w0 = f1w[lane*3], w1 = f1w[lane*3+1], w2 = f1w[lane*3+2], fb = f1b[lane];
    float sb[4];
    #pragma unroll
    for (int q = 0; q < 4; q++) sb[q] = stb[lane + 64*q];
    __syncthreads();
    int pt0 = blockIdx.x * 16 + w * 4;
    {
        int p = lane >> 4, k = lane & 15;
        int pt = pt0 + p, b = pt >> 11, m = pt & (cM - 1);
        int id = nidx[(size_t)pt * cK + k];
        #pragma unroll
        for (int c = 0; c < 3; c++)
            al4[w][p*48 + c*16 + k] = sp[((size_t)b*3 + c)*cN + id] - qp[((size_t)b*3 + c)*cM + m];
    }
    WAVE_SYNC();
    float ps1 = 0, pss1 = 0;
    #pragma unroll
    for (int p = 0; p < 4; p++)
        #pragma unroll
        for (int k = 0; k < 16; k++) {
            float a0 = al4[w][p*48 + k], a1 = al4[w][p*48 + 16 + k], a2 = al4[w][p*48 + 32 + k];
            float e = eluf(fb + w0*a0 + w1*a1 + w2*a2);
            ps1 += e; pss1 += e*e;
        }
    float acc[4][4];
    #pragma unroll
    for (int q = 0; q < 4; q++)
        #pragma unroll
        for (int p = 0; p < 4; p++) acc[q][p] = sb[q];
    #pragma unroll
    for (int j4 = 0; j4 < 12; j4++) {
        float4 a[4];
        #pragma unroll
        for (int p = 0; p < 4; p++) a[p] = *(const float4*)&al4[w][p*48 + j4*4];
        #pragma unroll
        for (int q = 0; q < 4; q++) {
            int o = lane + 64*q;
            float s0 = sw[o*49 + j4*4], s1 = sw[o*49 + j4*4+1], s2 = sw[o*49 + j4*4+2], s3 = sw[o*49 + j4*4+3];
            #pragma unroll
            for (int p = 0; p < 4; p++)
                acc[q][p] += s0*a[p].x + s1*a[p].y + s2*a[p].z + s3*a[p].w;
        }
    }
    float ps2[4] = {0,0,0,0}, pss2[4] = {0,0,0,0};
    #pragma unroll
    for (int q = 0; q < 4; q++)
        #pragma unroll
        for (int p = 0; p < 4; p++) {
            float e = eluf(acc[q][p]);
            ps2[q] += e; pss2[q] += e*e;
            ws[OFF_TST + (size_t)(pt0 + p)*256 + lane + 64*q] = e;
        }
    atomicAdd(&red[lane], ps1); atomicAdd(&red[64 + lane], pss1);
    #pragma unroll
    for (int q = 0; q < 4; q++) {
        atomicAdd(&red[128 + lane + 64*q], ps2[q]);
        atomicAdd(&red[384 + lane + 64*q], pss2[q]);
    }
    __syncthreads();
    if (t < 64) { atomicAdd(&ws[ACC_BN1 + t], red[t]); atomicAdd(&ws[ACC_BN1 + 64 + t], red[64 + t]); }
    atomicAdd(&ws[ACC_STEM + t], red[128 + t]); atomicAdd(&ws[ACC_STEM + 256 + t], red[384 + t]);
}

// ---- kE: stem(BN inline) -> grouped conv x1 -> store y1 post-ELU [pt][o] + x1 stats ----
__global__ __launch_bounds__(256) void kE(const float* __restrict__ x1w, const float* __restrict__ x1b,
        const float* __restrict__ stg, const float* __restrict__ stbe, float* __restrict__ ws) {
    __shared__ float xw[256 * 17];
    __shared__ float ts[4][4][256];
    __shared__ float red[512];
    int t = threadIdx.x, lane = t & 63, w = t >> 6;
    for (int l = t; l < 4096; l += 256) xw[(l >> 4)*17 + (l & 15)] = x1w[l];
    for (int l = t; l < 512; l += 256) red[l] = 0.f;
    float sscl[4], sshf[4];
    #pragma unroll
    for (int i = 0; i < 4; i++) {
        int ch = lane*4 + i;
        float mn = ws[ACC_STEM + ch] * (1.f/16384.f);
        float vr = ws[ACC_STEM + 256 + ch] * (1.f/16384.f) - mn*mn;
        float s = stg[ch] * rsqrtf(vr + cEPS);
        sscl[i] = s; sshf[i] = stbe[ch] - mn*s;
    }
    float xb[4];
    #pragma unroll
    for (int q = 0; q < 4; q++) xb[q] = x1b[lane + 64*q];
    __syncthreads();
    int pt0 = blockIdx.x * 16 + w * 4;
    #pragma unroll
    for (int p = 0; p < 4; p++) {
        float4 v = *(const float4*)&ws[OFF_TST + (size_t)(pt0 + p)*256 + lane*4];
        v.x = sscl[0]*v.x + sshf[0]; v.y = sscl[1]*v.y + sshf[1];
        v.z = sscl[2]*v.z + sshf[2]; v.w = sscl[3]*v.w + sshf[3];
        *(float4*)&ts[w][p][lane*4] = v;
    }
    WAVE_SYNC();
    float ps[4] = {0,0,0,0}, pss[4] = {0,0,0,0};
    #pragma unroll
    for (int q = 0; q < 4; q++) {
        int o = lane + 64*q, g = o >> 4;
        float accp[4] = {xb[q], xb[q], xb[q], xb[q]};
        #pragma unroll
        for (int j4 = 0; j4 < 4; j4++) {
            float s0 = xw[o*17 + j4*4], s1 = xw[o*17 + j4*4+1], s2 = xw[o*17 + j4*4+2], s3 = xw[o*17 + j4*4+3];
            #pragma unroll
            for (int p = 0; p < 4; p++) {
                float4 a = *(const float4*)&ts[w][p][g*16 + j4*4];
                accp[p] += s0*a.x + s1*a.y + s2*a.z + s3*a.w;
            }
        }
        #pragma unroll
        for (int p = 0; p < 4; p++) {
            float e = eluf(accp[p]);
            ps[q] += e; pss[q] += e*e;
            ws[OFF_Y1 + (size_t)(pt0 + p)*256 + o] = e;
        }
    }
    #pragma unroll
    for (int q = 0; q < 4; q++) {
        atomicAdd(&red[lane + 64*q], ps[q]);
        atomicAdd(&red[256 + lane + 64*q], pss[q]);
    }
    __syncthreads();
    atomicAdd(&ws[ACC_X1 + t], red[t]); atomicAdd(&ws[ACC_X1 + 256 + t], red[256 + t]);
}

// ---- kG: y1(BN_x1 inline, transposed stage) -> grouped conv x2 -> y2 [pt][o] + x2 stats ----
__global__ __launch_bounds__(256) void kG(const float* __restrict__ x2w, const float* __restrict__ x2b,
        const float* __restrict__ x1g, const float* __restrict__ x1be, float* __restrict__ ws) {
    __shared__ float xw[256 * 17];
    __shared__ float ts[4][4][256];    // stores S[g*16+j] = y1bn[j*16+g]
    __shared__ float red[512];
    int t = threadIdx.x, lane = t & 63, w = t >> 6;
    for (int l = t; l < 4096; l += 256) xw[(l >> 4)*17 + (l & 15)] = x2w[l];
    for (int l = t; l < 512; l += 256) red[l] = 0.f;
    float sscl[4], sshf[4];
    #pragma unroll
    for (int i = 0; i < 4; i++) {
        int ch = lane*4 + i;
        float mn = ws[ACC_X1 + ch] * (1.f/16384.f);
        float vr = ws[ACC_X1 + 256 + ch] * (1.f/16384.f) - mn*mn;
        float s = x1g[ch] * rsqrtf(vr + cEPS);
        sscl[i] = s; sshf[i] = x1be[ch] - mn*s;
    }
    float xb[4];
    #pragma unroll
    for (int q = 0; q < 4; q++) xb[q] = x2b[lane + 64*q];
    __syncthreads();
    int pt0 = blockIdx.x * 16 + w * 4;
    #pragma unroll
    for (int p = 0; p < 4; p++) {
        float4 v = *(const float4*)&ws[OFF_Y1 + (size_t)(pt0 + p)*256 + lane*4];
        float vv[4] = { sscl[0]*v.x + sshf[0], sscl[1]*v.y + sshf[1],
                        sscl[2]*v.z + sshf[2], sscl[3]*v.w + sshf[3] };
        #pragma unroll
        for (int i = 0; i < 4; i++) {
            int ch = lane*4 + i;
            ts[w][p][((ch & 15) << 4) | (ch >> 4)] = vv[i];
        }
    }
    WAVE_SYNC();
    float ps[4] = {0,0,0,0}, pss[4] = {0,0,0,0};
    #pragma unroll
    for (int q = 0; q < 4; q++) {
        int o = lane + 64*q, g = o >> 4;
        float accp[4] = {xb[q], xb[q], xb[q], xb[q]};
        #pragma unroll
        for (int j4 = 0; j4 < 4; j4++) {
            float s0 = xw[o*17 + j4*4], s1 = xw[o*17 + j4*4+1], s2 = xw[o*17 + j4*4+2], s3 = xw[o*17 + j4*4+3];
            #pragma unroll
            for (int p = 0; p < 4; p++) {
                float4 a = *(const float4*)&ts[w][p][g*16 + j4*4];
                accp[p] += s0*a.x + s1*a.y + s2*a.z + s3*a.w;
            }
        }
        #pragma unroll
        for (int p = 0; p < 4; p++) {
            float e = eluf(accp[p]);
            ps[q] += e; pss[q] += e*e;
            ws[OFF_Y2 + (size_t)(pt0 + p)*256 + o] = e;
        }
    }
    #pragma unroll
    for (int q = 0; q < 4; q++) {
        atomicAdd(&red[lane + 64*q], ps[q]);
        atomicAdd(&red[256 + lane + 64*q], pss[q]);
    }
    __syncthreads();
    atomicAdd(&ws[ACC_X2 + t], red[t]); atomicAdd(&ws[ACC_X2 + 256 + t], red[256 + t]);
}

// ---- kC: h1(BN1 inline) -> h2 post-ELU -> store bf16 TRANSPOSED [pt][o][k] + BN2 stats ----
// k chunked in halves of 8 to cap live registers (round-3 version spilled at acc[16]).
__global__ __launch_bounds__(256) void kC(const float* __restrict__ qp, const float* __restrict__ sp,
        const float* __restrict__ f1w, const float* __restrict__ f1b,
        const float* __restrict__ f2w, const float* __restrict__ f2b,
        const float* __restrict__ f1g, const float* __restrict__ f1be,
        const int* __restrict__ nidx, float* __restrict__ ws) {
    __shared__ float f2t[4096];        // [c][o] transposed -> per-lane stride-64 reads (2-way, free)
    __shared__ float h1s[4][1024];     // per wave: [k*64+c]
    __shared__ float al4[4][48];
    __shared__ float red[128];
    uint32_t* h2p = (uint32_t*)(ws + OFF_TST);   // packed bf16 pairs, [pt][o][k/2]
    int t = threadIdx.x, lane = t & 63, w = t >> 6;
    for (int l = t; l < 4096; l += 256) f2t[l] = f2w[(size_t)(l & 63)*64 + (l >> 6)];
    if (t < 128) red[t] = 0.f;
    float w0 = f1w[lane*3], w1 = f1w[lane*3+1], w2 = f1w[lane*3+2], fb = f1b[lane];
    float s1, sh1;
    {
        float mn = ws[ACC_BN1 + lane] * (1.f/262144.f);
        float vr = ws[ACC_BN1 + 64 + lane] * (1.f/262144.f) - mn*mn;
        s1 = f1g[lane] * rsqrtf(vr + cEPS);
        sh1 = f1be[lane] - mn*s1;
    }
    float f2bv = f2b[lane];
    __syncthreads();
    int pt0 = blockIdx.x * 16 + w * 4;
    float ps = 0, pss = 0;
    for (int p = 0; p < 4; p++) {
        int pt = pt0 + p, b = pt >> 11, m = pt & (cM - 1);
        if (lane < 48) {
            int c = lane >> 4, k = lane & 15;
            int id = nidx[(size_t)pt * cK + k];
            al4[w][c*16 + k] = sp[((size_t)b*3 + c)*cN + id] - qp[((size_t)b*3 + c)*cM + m];
        }
        WAVE_SYNC();
        #pragma unroll
        for (int k = 0; k < 16; k++) {
            float a0 = al4[w][k], a1 = al4[w][16 + k], a2 = al4[w][32 + k];
            h1s[w][k*64 + lane] = s1 * eluf(fb + w0*a0 + w1*a1 + w2*a2) + sh1;
        }
        WAVE_SYNC();
        #pragma unroll
        for (int half = 0; half < 2; half++) {
            float acc0 = f2bv, acc1 = f2bv, acc2 = f2bv, acc3 = f2bv;
            float acc4 = f2bv, acc5 = f2bv, acc6 = f2bv, acc7 = f2bv;
            int kb = half * 8 * 64;
            #pragma unroll
            for (int c0 = 0; c0 < 64; c0 += 4) {
                float g0 = f2t[(c0+0)*64 + lane], g1 = f2t[(c0+1)*64 + lane];
                float g2 = f2t[(c0+2)*64 + lane], g3 = f2t[(c0+3)*64 + lane];
                float4 h0 = *(const float4*)&h1s[w][kb + 0*64 + c0];
                float4 h1 = *(const float4*)&h1s[w][kb + 1*64 + c0];
                float4 h2 = *(const float4*)&h1s[w][kb + 2*64 + c0];
                float4 h3 = *(const float4*)&h1s[w][kb + 3*64 + c0];
                acc0 += g0*h0.x + g1*h0.y + g2*h0.z + g3*h0.w;
                acc1 += g0*h1.x + g1*h1.y + g2*h1.z + g3*h1.w;
                acc2 += g0*h2.x + g1*h2.y + g2*h2.z + g3*h2.w;
                acc3 += g0*h3.x + g1*h3.y + g2*h3.z + g3*h3.w;
                float4 h4 = *(const float4*)&h1s[w][kb + 4*64 + c0];
                float4 h5 = *(const float4*)&h1s[w][kb + 5*64 + c0];
                float4 h6 = *(const float4*)&h1s[w][kb + 6*64 + c0];
                float4 h7 = *(const float4*)&h1s[w][kb + 7*64 + c0];
                acc4 += g0*h4.x + g1*h4.y + g2*h4.z + g3*h4.w;
                acc5 += g0*h5.x + g1*h5.y + g2*h5.z + g3*h5.w;
                acc6 += g0*h6.x + g1*h6.y + g2*h6.z + g3*h6.w;
                acc7 += g0*h7.x + g1*h7.y + g2*h7.z + g3*h7.w;
            }
            float e0 = eluf(acc0), e1 = eluf(acc1), e2 = eluf(acc2), e3 = eluf(acc3);
            float e4 = eluf(acc4), e5 = eluf(acc5), e6 = eluf(acc6), e7 = eluf(acc7);
            ps  += e0+e1+e2+e3+e4+e5+e6+e7;
            pss += e0*e0+e1*e1+e2*e2+e3*e3+e4*e4+e5*e5+e6*e6+e7*e7;
            uint4 pkd = make_uint4(pk2bf(e0,e1), pk2bf(e2,e3), pk2bf(e4,e5), pk2bf(e6,e7));
            *(uint4*)(h2p + (size_t)pt*512 + lane*8 + half*4) = pkd;
        }
        WAVE_SYNC();   // al4/h1s reused next p
    }
    atomicAdd(&red[lane], ps); atomicAdd(&red[64 + lane], pss);
    __syncthreads();
    if (t < 64) { atomicAdd(&ws[ACC_BN2 + t], red[t]); atomicAdd(&ws[ACC_BN2 + 64 + t], red[64 + t]); }
}

// ---- kI: wave-per-point gather+qf+depthwise. nf channels in registers. ----
__global__ __launch_bounds__(256) void kI(const float* __restrict__ dww,
        const float* __restrict__ f2g, const float* __restrict__ f2be,
        const float* __restrict__ x2g, const float* __restrict__ x2be,
        const int* __restrict__ nidx, float* __restrict__ ws) {
    __shared__ float dws[192 * 17];    // [c][l] pad 17
    __shared__ float xs[4][256];       // per wave x matrix [k*16+l]
    const uint32_t* h2p = (const uint32_t*)(ws + OFF_TST);
    int t = threadIdx.x, lane = t & 63, w = t >> 6;
    for (int l = t; l < 3072; l += 256) dws[(l >> 4)*17 + (l & 15)] = dww[l];
    float sx[4], shx[4];
    #pragma unroll
    for (int i = 0; i < 4; i++) {
        int ch = lane*4 + i;
        float mn = ws[ACC_X2 + ch] * (1.f/16384.f);
        float vr = ws[ACC_X2 + 256 + ch] * (1.f/16384.f) - mn*mn;
        float s = x2g[ch] * rsqrtf(vr + cEPS);
        sx[i] = s; shx[i] = x2be[ch] - mn*s;
    }
    float s2, sh2;
    {
        float mn = ws[ACC_BN2 + lane] * (1.f/262144.f);
        float vr = ws[ACC_BN2 + 64 + lane] * (1.f/262144.f) - mn*mn;
        s2 = f2g[lane] * rsqrtf(vr + cEPS);
        sh2 = f2be[lane] - mn*s2;
    }
    __syncthreads();
    int pt0 = blockIdx.x * 8 + w * 2;
    for (int p = 0; p < 2; p++) {
        int pt = pt0 + p, b = pt >> 11;
        const int4* ip = (const int4*)(nidx + (size_t)pt * cK);
        int4 iA = ip[0], iB = ip[1], iC2 = ip[2], iD = ip[3];
        int idxv[16] = {iA.x, iA.y, iA.z, iA.w, iB.x, iB.y, iB.z, iB.w,
                        iC2.x, iC2.y, iC2.z, iC2.w, iD.x, iD.y, iD.z, iD.w};
        // gather s_feats rows: channels lane, lane+64 in regs
        float nfa[16], nfb[16];
        #pragma unroll
        for (int k = 0; k < 16; k++) {
            const float* rp = ws + OFF_SFT + ((size_t)b*cN + idxv[k]) * cC;
            nfa[k] = rp[lane];
            nfb[k] = rp[lane + 64];
        }
        // h2 (third channel block) with BN2 affine -> regs (packed bf16 pairs)
        float nfh[16];
        {
            const uint4* srcq = (const uint4*)(h2p + (size_t)pt*512 + lane*8);
            uint4 ha = srcq[0], hbq = srcq[1];
            nfh[0]  = s2*bf_lo(ha.x)  + sh2; nfh[1]  = s2*bf_hi(ha.x)  + sh2;
            nfh[2]  = s2*bf_lo(ha.y)  + sh2; nfh[3]  = s2*bf_hi(ha.y)  + sh2;
            nfh[4]  = s2*bf_lo(ha.z)  + sh2; nfh[5]  = s2*bf_hi(ha.z)  + sh2;
            nfh[6]  = s2*bf_lo(ha.w)  + sh2; nfh[7]  = s2*bf_hi(ha.w)  + sh2;
            nfh[8]  = s2*bf_lo(hbq.x) + sh2; nfh[9]  = s2*bf_hi(hbq.x) + sh2;
            nfh[10] = s2*bf_lo(hbq.y) + sh2; nfh[11] = s2*bf_hi(hbq.y) + sh2;
            nfh[12] = s2*bf_lo(hbq.z) + sh2; nfh[13] = s2*bf_hi(hbq.z) + sh2;
            nfh[14] = s2*bf_lo(hbq.w) + sh2; nfh[15] = s2*bf_hi(hbq.w) + sh2;
        }
        // x matrix into per-wave LDS
        {
            float4 v = *(const float4*)&ws[OFF_Y2 + (size_t)pt*256 + lane*4];
            v.x = sx[0]*v.x + shx[0]; v.y = sx[1]*v.y + shx[1];
            v.z = sx[2]*v.z + shx[2]; v.w = sx[3]*v.w + shx[3];
            *(float4*)&xs[w][lane*4] = v;
        }
        WAVE_SYNC();
        // pass 1: channel lane+128 (h2)
        float qc[16];
        #pragma unroll
        for (int l = 0; l < 16; l++) qc[l] = 0.f;
        #pragma unroll
        for (int k = 0; k < 16; k++) {
            float4 x0 = *(const float4*)&xs[w][k*16 + 0];
            float4 x1 = *(const float4*)&xs[w][k*16 + 4];
            float4 x2v = *(const float4*)&xs[w][k*16 + 8];
            float4 x3 = *(const float4*)&xs[w][k*16 + 12];
            float nh = nfh[k];
            qc[0] += nh*x0.x; qc[1] += nh*x0.y; qc[2]  += nh*x0.z; qc[3]  += nh*x0.w;
            qc[4] += nh*x1.x; qc[5] += nh*x1.y; qc[6]  += nh*x1.z; qc[7]  += nh*x1.w;
            qc[8] += nh*x2v.x; qc[9] += nh*x2v.y; qc[10] += nh*x2v.z; qc[11] += nh*x2v.w;
            qc[12] += nh*x3.x; qc[13] += nh*x3.y; qc[14] += nh*x3.z; qc[15] += nh*x3.w;
        }
        float dc = 0;
        #pragma unroll
        for (int l = 0; l < 16; l++) dc += qc[l] * dws[(lane + 128)*17 + l];
        // pass 2: channels lane, lane+64 (gathered)
        float qa[16], qb[16];
        #pragma unroll
        for (int l = 0; l < 16; l++) { qa[l] = 0.f; qb[l] = 0.f; }
        #pragma unroll
        for (int k = 0; k < 16; k++) {
            float4 x0 = *(const float4*)&xs[w][k*16 + 0];
            float4 x1 = *(const float4*)&xs[w][k*16 + 4];
            float4 x2v = *(const float4*)&xs[w][k*16 + 8];
            float4 x3 = *(const float4*)&xs[w][k*16 + 12];
            float na = nfa[k], nb = nfb[k];
            qa[0] += na*x0.x; qa[1] += na*x0.y; qa[2]  += na*x0.z; qa[3]  += na*x0.w;
            qa[4] += na*x1.x; qa[5] += na*x1.y; qa[6]  += na*x1.z; qa[7]  += na*x1.w;
            qa[8] += na*x2v.x; qa[9] += na*x2v.y; qa[10] += na*x2v.z; qa[11] += na*x2v.w;
            qa[12] += na*x3.x; qa[13] += na*x3.y; qa[14] += na*x3.z; qa[15] += na*x3.w;
            qb[0] += nb*x0.x; qb[1] += nb*x0.y; qb[2]  += nb*x0.z; qb[3]  += nb*x0.w;
            qb[4] += nb*x1.x; qb[5] += nb*x1.y; qb[6]  += nb*x1.z; qb[7]  += nb*x1.w;
            qb[8] += nb*x2v.x; qb[9] += nb*x2v.y; qb[10] += nb*x2v.z; qb[11] += nb*x2v.w;
            qb[12] += nb*x3.x; qb[13] += nb*x3.y; qb[14] += nb*x3.z; qb[15] += nb*x3.w;
        }
        float da = 0, db = 0;
        #pragma unroll
        for (int l = 0; l < 16; l++) {
            da += qa[l] * dws[lane*17 + l];
            db += qb[l] * dws[(lane + 64)*17 + l];
        }
        float* op = ws + OFF_DW + (size_t)pt * cCH;
        op[lane] = da; op[lane + 64] = db; op[lane + 128] = dc;
        WAVE_SYNC();   // xs reused next p
    }
}

// ---- kJ: [16384x192]x[192x256] GEMM + bias + ELU + final stats ----
__global__ __launch_bounds__(256) void kJ(const float* __restrict__ pww, const float* __restrict__ pwb,
                                          float* __restrict__ ws, float* __restrict__ out) {
    __shared__ float As[16][65];
    __shared__ float Bs[16][65];
    int t = threadIdx.x;
    int tx = t & 15, ty = t >> 4;
    int p0 = blockIdx.x * 64, o0 = blockIdx.y * 64;
    float acc[4][4];
    #pragma unroll
    for (int i = 0; i < 4; i++)
        #pragma unroll
        for (int j = 0; j < 4; j++) acc[i][j] = 0.f;
    int la = t * 4;
    int apl = la >> 4, akl = la & 15;
    for (int kt = 0; kt < 12; kt++) {
        float4 av = *(const float4*)&ws[OFF_DW + (size_t)(p0 + apl)*cCH + kt*16 + akl];
        float4 bv = *(const float4*)&pww[(size_t)(o0 + apl)*cCH + kt*16 + akl];
        As[akl][apl] = av.x; As[akl+1][apl] = av.y; As[akl+2][apl] = av.z; As[akl+3][apl] = av.w;
        Bs[akl][apl] = bv.x; Bs[akl+1][apl] = bv.y; Bs[akl+2][apl] = bv.z; Bs[akl+3][apl] = bv.w;
        __syncthreads();
        #pragma unroll
        for (int kk = 0; kk < 16; kk++) {
            float a0 = As[kk][tx*4], a1 = As[kk][tx*4+1], a2 = As[kk][tx*4+2], a3 = As[kk][tx*4+3];
            float b0 = Bs[kk][ty*4], b1 = Bs[kk][ty*4+1], b2 = Bs[kk][ty*4+2], b3 = Bs[kk][ty*4+3];
            acc[0][0]+=a0*b0; acc[0][1]+=a0*b1; acc[0][2]+=a0*b2; acc[0][3]+=a0*b3;
            acc[1][0]+=a1*b0; acc[1][1]+=a1*b1; acc[1][2]+=a1*b2; acc[1][3]+=a1*b3;
            acc[2][0]+=a2*b0; acc[2][1]+=a2*b1; acc[2][2]+=a2*b2; acc[2][3]+=a2*b3;
            acc[3][0]+=a3*b0; acc[3][1]+=a3*b1; acc[3][2]+=a3*b2; acc[3][3]+=a3*b3;
        }
        __syncthreads();
    }
    int b = p0 >> 11, mb = (p0 & (cM - 1)) + tx*4;
    #pragma unroll
    for (int j = 0; j < 4; j++) {
        int oo = o0 + ty*4 + j;
        float pb = pwb[oo];
        float e0 = eluf(acc[0][j] + pb), e1 = eluf(acc[1][j] + pb);
        float e2 = eluf(acc[2][j] + pb), e3 = eluf(acc[3][j] + pb);
        float sum = e0+e1+e2+e3, ssq = e0*e0+e1*e1+e2*e2+e3*e3;
        #pragma unroll
        for (int off = 1; off < 16; off <<= 1) { sum += __shfl_xor(sum, off); ssq += __shfl_xor(ssq, off); }
        if (tx == 0) { atomicAdd(&ws[ACC_FIN + oo], sum); atomicAdd(&ws[ACC_FIN + 256 + oo], ssq); }
        float4 st = make_float4(e0, e1, e2, e3);
        *(float4*)&out[((size_t)b*cO + oo)*cM + mb] = st;
    }
}

// ---- kK: final BN affine in-place (inline finalize) ----
__global__ __launch_bounds__(256) void kK(float* __restrict__ out, const float* __restrict__ ws,
        const float* __restrict__ sepg, const float* __restrict__ sepbe) {
    int i = blockIdx.x * 256 + threadIdx.x;
    if (i < (cB*cO*cM) / 4) {
        int o = (i >> 9) & 255;
        float mn = ws[ACC_FIN + o] * (1.f/16384.f);
        float vr = ws[ACC_FIN + 256 + o] * (1.f/16384.f) - mn*mn;
        float s = sepg[o] * rsqrtf(vr + cEPS);
        float sh = sepbe[o] - mn*s;
        float4 v = ((float4*)out)[i];
        v.x = s*v.x + sh; v.y = s*v.y + sh; v.z = s*v.z + sh; v.w = s*v.w + sh;
        ((float4*)out)[i] = v;
    }
}

extern "C" void kernel_launch(void* const* d_in, const int* in_sizes, int n_in,
                              void* d_out, int out_size, void* d_ws, size_t ws_size,
                              hipStream_t stream) {
    const float* qp   = (const float*)d_in[0];
    const float* sp   = (const float*)d_in[1];
    const float* sf   = (const float*)d_in[2];
    const float* f1w  = (const float*)d_in[3];
    const float* f1b  = (const float*)d_in[4];
    const float* f1g  = (const float*)d_in[5];
    const float* f1be = (const float*)d_in[6];
    const float* f2w  = (const float*)d_in[7];
    const float* f2b  = (const float*)d_in[8];
    const float* f2g  = (const float*)d_in[9];
    const float* f2be = (const float*)d_in[10];
    const float* stw  = (const float*)d_in[11];
    const float* stb  = (const float*)d_in[12];
    const float* stg  = (const float*)d_in[13];
    const float* stbe = (const float*)d_in[14];
    const float* x1w  = (const float*)d_in[15];
    const float* x1b  = (const float*)d_in[16];
    const float* x1g  = (const float*)d_in[17];
    const float* x1be = (const float*)d_in[18];
    const float* x2w  = (const float*)d_in[19];
    const float* x2b  = (const float*)d_in[20];
    const float* x2g  = (const float*)d_in[21];
    const float* x2be = (const float*)d_in[22];
    const float* dww  = (const float*)d_in[23];
    const float* pww  = (const float*)d_in[24];
    const float* pwb  = (const float*)d_in[25];
    const float* sepg = (const float*)d_in[26];
    const float* sepbe= (const float*)d_in[27];
    const int*   nidx = (const int*)d_in[28];
    float* ws  = (float*)d_ws;
    float* out = (float*)d_out;
    if (ws_size < WS_FLOATS * sizeof(float)) return;

    hipMemsetAsync(d_ws, 0, 2304 * sizeof(float), stream);  // zero stat accumulators
    k_tr<<<dim3(cN/32, cC/32, cB), dim3(32, 8), 0, stream>>>(sf, ws + OFF_SFT);
    kA<<<NPTS/16, 256, 0, stream>>>(qp, sp, f1w, f1b, stw, stb, nidx, ws);
    kE<<<NPTS/16, 256, 0, stream>>>(x1w, x1b, stg, stbe, ws);
    kG<<<NPTS/16, 256, 0, stream>>>(x2w, x2b, x1g, x1be, ws);
    kC<<<NPTS/16, 256, 0, stream>>>(qp, sp, f1w, f1b, f2w, f2b, f1g, f1be, nidx, ws);
    kI<<<NPTS/8,  256, 0, stream>>>(dww, f2g, f2be, x2g, x2be, nidx, ws);
    kJ<<<dim3(NPTS/64, cO/64), 256, 0, stream>>>(pww, pwb, ws, out);
    kK<<<(cB*cO*cM/4 + 255)/256, 256, 0, stream>>>(out, ws, sepg, sepbe);
}

// Round 5
// 353.641 us; speedup vs baseline: 3.8818x; 1.4004x over previous
//
#include <hip/hip_runtime.h>
#include <hip/hip_bf16.h>
#include <cstddef>
#include <cstdint>

constexpr int cB = 8, cN = 8192, cM = 2048, cK = 16, cC = 128, cH = 64, cO = 256, cCH = 192;
constexpr int NPTS = cB * cM;        // 16384
constexpr float cEPS = 1e-5f;

typedef __attribute__((ext_vector_type(8))) short short8;
typedef __attribute__((ext_vector_type(4))) float f32x4;

// ---- workspace layout (float offsets) ----
constexpr size_t ACC_BN1 = 0, ACC_BN2 = 128, ACC_STEM = 256, ACC_X1 = 768, ACC_X2 = 1280, ACC_FIN = 1792;
constexpr size_t OFF_SFT = 8192;                                  // s_feats transposed [B,N,C] f32
constexpr size_t OFF_TST = OFF_SFT + (size_t)cB * cN * cC;        // stem post-ELU [NPTS,256] f32; later h2T bf16 [NPTS,64,16]
constexpr size_t OFF_Y1  = OFF_TST + (size_t)NPTS * 256;          // y1 post-ELU  [NPTS,256] f32
constexpr size_t OFF_Y2  = OFF_Y1  + (size_t)NPTS * 256;          // y2 post-ELU  [NPTS,256] f32
constexpr size_t OFF_DW  = OFF_Y2  + (size_t)NPTS * 256;          // dw matrix    [NPTS,192] f32
constexpr size_t WS_FLOATS = OFF_DW + (size_t)NPTS * cCH;

__device__ __forceinline__ float eluf(float x) { return x > 0.f ? x : expm1f(x); }

// pack two f32 -> two bf16 (RNE) in one u32: low = a, high = b. Pure reg ops, no arrays.
__device__ __forceinline__ uint32_t pk2bf(float a, float b) {
    uint32_t ua = __float_as_uint(a); ua += 0x7FFFu + ((ua >> 16) & 1u);
    uint32_t ub = __float_as_uint(b); ub += 0x7FFFu + ((ub >> 16) & 1u);
    return (ua >> 16) | (ub & 0xFFFF0000u);
}
__device__ __forceinline__ float bf_lo(uint32_t u) { return __uint_as_float(u << 16); }
__device__ __forceinline__ float bf_hi(uint32_t u) { return __uint_as_float(u & 0xFFFF0000u); }
__device__ __forceinline__ short f2bf_s(float a) {
    uint32_t ua = __float_as_uint(a); ua += 0x7FFFu + ((ua >> 16) & 1u);
    return (short)(ua >> 16);
}

// wave-internal LDS visibility: wave64 is lockstep; DS ops counted by lgkmcnt.
#define WAVE_SYNC() do { asm volatile("s_waitcnt lgkmcnt(0)" ::: "memory"); \
                         __builtin_amdgcn_sched_barrier(0); } while (0)

// ---- transpose s_feats [B,C,N] -> [B,N,C] ----
__global__ __launch_bounds__(256) void k_tr(const float* __restrict__ sf, float* __restrict__ sfT) {
    __shared__ float tile[32][33];
    int b = blockIdx.z, n0 = blockIdx.x * 32, c0 = blockIdx.y * 32;
    int tx = threadIdx.x, ty = threadIdx.y;
    #pragma unroll
    for (int j = 0; j < 32; j += 8)
        tile[ty + j][tx] = sf[((size_t)b * cC + (c0 + ty + j)) * cN + n0 + tx];
    __syncthreads();
    #pragma unroll
    for (int j = 0; j < 32; j += 8)
        sfT[((size_t)b * cN + (n0 + ty + j)) * cC + c0 + tx] = tile[tx][ty + j];
}

// ---- kA: BN1 (h1) stats + stem conv (store post-ELU [pt][o]) + stem stats ----
__global__ __launch_bounds__(256) void kA(const float* __restrict__ qp, const float* __restrict__ sp,
        const float* __restrict__ f1w, const float* __restrict__ f1b,
        const float* __restrict__ stw, const float* __restrict__ stb,
        const int* __restrict__ nidx, float* __restrict__ ws) {
    __shared__ float sw[256 * 49];     // [o][j] pad 49 -> 2-way free
    __shared__ float al4[4][192];      // per wave: [p][c*16+k]
    __shared__ float red[640];         // 0..127 BN1, 128..639 stem
    int t = threadIdx.x, lane = t & 63, w = t >> 6;
    for (int l = t; l < 256 * 48; l += 256) sw[(l / 48) * 49 + (l % 48)] = stw[l];
    for (int l = t; l < 640; l += 256) red[l] = 0.f;
    float w0 = f1w[lane*3], w1 = f1w[lane*3+1], w2 = f1w[lane*3+2], fb = f1b[lane];
    float sb[4];
    #pragma unroll
    for (int q = 0; q < 4; q++) sb[q] = stb[lane + 64*q];
    __syncthreads();
    int pt0 = blockIdx.x * 16 + w * 4;
    {
        int p = lane >> 4, k = lane & 15;
        int pt = pt0 + p, b = pt >> 11, m = pt & (cM - 1);
        int id = nidx[(size_t)pt * cK + k];
        #pragma unroll
        for (int c = 0; c < 3; c++)
            al4[w][p*48 + c*16 + k] = sp[((size_t)b*3 + c)*cN + id] - qp[((size_t)b*3 + c)*cM + m];
    }
    WAVE_SYNC();
    float ps1 = 0, pss1 = 0;
    #pragma unroll
    for (int p = 0; p < 4; p++)
        #pragma unroll
        for (int k = 0; k < 16; k++) {
            float a0 = al4[w][p*48 + k], a1 = al4[w][p*48 + 16 + k], a2 = al4[w][p*48 + 32 + k];
            float e = eluf(fb + w0*a0 + w1*a1 + w2*a2);
            ps1 += e; pss1 += e*e;
        }
    float acc[4][4];
    #pragma unroll
    for (int q = 0; q < 4; q++)
        #pragma unroll
        for (int p = 0; p < 4; p++) acc[q][p] = sb[q];
    #pragma unroll
    for (int j4 = 0; j4 < 12; j4++) {
        float4 a[4];
        #pragma unroll
        for (int p = 0; p < 4; p++) a[p] = *(const float4*)&al4[w][p*48 + j4*4];
        #pragma unroll
        for (int q = 0; q < 4; q++) {
            int o = lane + 64*q;
            float s0 = sw[o*49 + j4*4], s1 = sw[o*49 + j4*4+1], s2 = sw[o*49 + j4*4+2], s3 = sw[o*49 + j4*4+3];
            #pragma unroll
            for (int p = 0; p < 4; p++)
                acc[q][p] += s0*a[p].x + s1*a[p].y + s2*a[p].z + s3*a[p].w;
        }
    }
    float ps2[4] = {0,0,0,0}, pss2[4] = {0,0,0,0};
    #pragma unroll
    for (int q = 0; q < 4; q++)
        #pragma unroll
        for (int p = 0; p < 4; p++) {
            float e = eluf(acc[q][p]);
            ps2[q] += e; pss2[q] += e*e;
            ws[OFF_TST + (size_t)(pt0 + p)*256 + lane + 64*q] = e;
        }
    atomicAdd(&red[lane], ps1); atomicAdd(&red[64 + lane], pss1);
    #pragma unroll
    for (int q = 0; q < 4; q++) {
        atomicAdd(&red[128 + lane + 64*q], ps2[q]);
        atomicAdd(&red[384 + lane + 64*q], pss2[q]);
    }
    __syncthreads();
    if (t < 64) { atomicAdd(&ws[ACC_BN1 + t], red[t]); atomicAdd(&ws[ACC_BN1 + 64 + t], red[64 + t]); }
    atomicAdd(&ws[ACC_STEM + t], red[128 + t]); atomicAdd(&ws[ACC_STEM + 256 + t], red[384 + t]);
}

// ---- kE: stem(BN inline) -> grouped conv x1 -> store y1 post-ELU [pt][o] + x1 stats ----
__global__ __launch_bounds__(256) void kE(const float* __restrict__ x1w, const float* __restrict__ x1b,
        const float* __restrict__ stg, const float* __restrict__ stbe, float* __restrict__ ws) {
    __shared__ float xw[256 * 17];
    __shared__ float ts[4][4][256];
    __shared__ float red[512];
    int t = threadIdx.x, lane = t & 63, w = t >> 6;
    for (int l = t; l < 4096; l += 256) xw[(l >> 4)*17 + (l & 15)] = x1w[l];
    for (int l = t; l < 512; l += 256) red[l] = 0.f;
    float sscl[4], sshf[4];
    #pragma unroll
    for (int i = 0; i < 4; i++) {
        int ch = lane*4 + i;
        float mn = ws[ACC_STEM + ch] * (1.f/16384.f);
        float vr = ws[ACC_STEM + 256 + ch] * (1.f/16384.f) - mn*mn;
        float s = stg[ch] * rsqrtf(vr + cEPS);
        sscl[i] = s; sshf[i] = stbe[ch] - mn*s;
    }
    float xb[4];
    #pragma unroll
    for (int q = 0; q < 4; q++) xb[q] = x1b[lane + 64*q];
    __syncthreads();
    int pt0 = blockIdx.x * 16 + w * 4;
    #pragma unroll
    for (int p = 0; p < 4; p++) {
        float4 v = *(const float4*)&ws[OFF_TST + (size_t)(pt0 + p)*256 + lane*4];
        v.x = sscl[0]*v.x + sshf[0]; v.y = sscl[1]*v.y + sshf[1];
        v.z = sscl[2]*v.z + sshf[2]; v.w = sscl[3]*v.w + sshf[3];
        *(float4*)&ts[w][p][lane*4] = v;
    }
    WAVE_SYNC();
    float ps[4] = {0,0,0,0}, pss[4] = {0,0,0,0};
    #pragma unroll
    for (int q = 0; q < 4; q++) {
        int o = lane + 64*q, g = o >> 4;
        float accp[4] = {xb[q], xb[q], xb[q], xb[q]};
        #pragma unroll
        for (int j4 = 0; j4 < 4; j4++) {
            float s0 = xw[o*17 + j4*4], s1 = xw[o*17 + j4*4+1], s2 = xw[o*17 + j4*4+2], s3 = xw[o*17 + j4*4+3];
            #pragma unroll
            for (int p = 0; p < 4; p++) {
                float4 a = *(const float4*)&ts[w][p][g*16 + j4*4];
                accp[p] += s0*a.x + s1*a.y + s2*a.z + s3*a.w;
            }
        }
        #pragma unroll
        for (int p = 0; p < 4; p++) {
            float e = eluf(accp[p]);
            ps[q] += e; pss[q] += e*e;
            ws[OFF_Y1 + (size_t)(pt0 + p)*256 + o] = e;
        }
    }
    #pragma unroll
    for (int q = 0; q < 4; q++) {
        atomicAdd(&red[lane + 64*q], ps[q]);
        atomicAdd(&red[256 + lane + 64*q], pss[q]);
    }
    __syncthreads();
    atomicAdd(&ws[ACC_X1 + t], red[t]); atomicAdd(&ws[ACC_X1 + 256 + t], red[256 + t]);
}

// ---- kG: y1(BN_x1 inline, transposed stage) -> grouped conv x2 -> y2 [pt][o] + x2 stats ----
__global__ __launch_bounds__(256) void kG(const float* __restrict__ x2w, const float* __restrict__ x2b,
        const float* __restrict__ x1g, const float* __restrict__ x1be, float* __restrict__ ws) {
    __shared__ float xw[256 * 17];
    __shared__ float ts[4][4][256];    // stores S[g*16+j] = y1bn[j*16+g]
    __shared__ float red[512];
    int t = threadIdx.x, lane = t & 63, w = t >> 6;
    for (int l = t; l < 4096; l += 256) xw[(l >> 4)*17 + (l & 15)] = x2w[l];
    for (int l = t; l < 512; l += 256) red[l] = 0.f;
    float sscl[4], sshf[4];
    #pragma unroll
    for (int i = 0; i < 4; i++) {
        int ch = lane*4 + i;
        float mn = ws[ACC_X1 + ch] * (1.f/16384.f);
        float vr = ws[ACC_X1 + 256 + ch] * (1.f/16384.f) - mn*mn;
        float s = x1g[ch] * rsqrtf(vr + cEPS);
        sscl[i] = s; sshf[i] = x1be[ch] - mn*s;
    }
    float xb[4];
    #pragma unroll
    for (int q = 0; q < 4; q++) xb[q] = x2b[lane + 64*q];
    __syncthreads();
    int pt0 = blockIdx.x * 16 + w * 4;
    #pragma unroll
    for (int p = 0; p < 4; p++) {
        float4 v = *(const float4*)&ws[OFF_Y1 + (size_t)(pt0 + p)*256 + lane*4];
        float vv[4] = { sscl[0]*v.x + sshf[0], sscl[1]*v.y + sshf[1],
                        sscl[2]*v.z + sshf[2], sscl[3]*v.w + sshf[3] };
        #pragma unroll
        for (int i = 0; i < 4; i++) {
            int ch = lane*4 + i;
            ts[w][p][((ch & 15) << 4) | (ch >> 4)] = vv[i];
        }
    }
    WAVE_SYNC();
    float ps[4] = {0,0,0,0}, pss[4] = {0,0,0,0};
    #pragma unroll
    for (int q = 0; q < 4; q++) {
        int o = lane + 64*q, g = o >> 4;
        float accp[4] = {xb[q], xb[q], xb[q], xb[q]};
        #pragma unroll
        for (int j4 = 0; j4 < 4; j4++) {
            float s0 = xw[o*17 + j4*4], s1 = xw[o*17 + j4*4+1], s2 = xw[o*17 + j4*4+2], s3 = xw[o*17 + j4*4+3];
            #pragma unroll
            for (int p = 0; p < 4; p++) {
                float4 a = *(const float4*)&ts[w][p][g*16 + j4*4];
                accp[p] += s0*a.x + s1*a.y + s2*a.z + s3*a.w;
            }
        }
        #pragma unroll
        for (int p = 0; p < 4; p++) {
            float e = eluf(accp[p]);
            ps[q] += e; pss[q] += e*e;
            ws[OFF_Y2 + (size_t)(pt0 + p)*256 + o] = e;
        }
    }
    #pragma unroll
    for (int q = 0; q < 4; q++) {
        atomicAdd(&red[lane + 64*q], ps[q]);
        atomicAdd(&red[256 + lane + 64*q], pss[q]);
    }
    __syncthreads();
    atomicAdd(&ws[ACC_X2 + t], red[t]); atomicAdd(&ws[ACC_X2 + 256 + t], red[256 + t]);
}

// ---- kC v3: MFMA h2. BN1 folded into weights: h2 = W'.h1raw + b', W'[o][c]=f2w[o][c]*s1[c].
// Per wave/point: h1raw bf16 -> swizzled LDS tile; A-frags (2 x ds_read_b128); 8 MFMA 16x16x32.
__global__ __launch_bounds__(256) void kC(const float* __restrict__ qp, const float* __restrict__ sp,
        const float* __restrict__ f1w, const float* __restrict__ f1b,
        const float* __restrict__ f2w, const float* __restrict__ f2b,
        const float* __restrict__ f1g, const float* __restrict__ f1be,
        const int* __restrict__ nidx, float* __restrict__ ws) {
    __shared__ float al4[4][48];
    __shared__ __align__(16) unsigned char h1l[4][2048];  // per-wave bf16[16][64], byte ^= (k&7)<<4
    __shared__ float s1s[64], sh1s[64], b2s[64];
    __shared__ float red[128];
    uint32_t* h2p = (uint32_t*)(ws + OFF_TST);
    int t = threadIdx.x, lane = t & 63, w = t >> 6;
    if (t < 128) red[t] = 0.f;
    if (t < 64) {
        float mn = ws[ACC_BN1 + t] * (1.f/262144.f);
        float vr = ws[ACC_BN1 + 64 + t] * (1.f/262144.f) - mn*mn;
        float s = f1g[t] * rsqrtf(vr + cEPS);
        s1s[t] = s; sh1s[t] = f1be[t] - mn*s;
    }
    __syncthreads();
    // h1 params for channel c = lane
    float w0 = f1w[lane*3], w1 = f1w[lane*3+1], w2 = f1w[lane*3+2], fb = f1b[lane];
    int ncol = lane & 15, g = lane >> 4;
    // b'[o] = f2b[o] + sum_c f2w[o][c]*sh1[c]
    if (t < 64) {
        float a = f2b[t];
        const float* fr = f2w + (size_t)t*64;
        #pragma unroll 8
        for (int c = 0; c < 64; c++) a += fr[c] * sh1s[c];
        b2s[t] = a;
    }
    // B fragments: W'[o][c], lane: o = tt*16+ncol, c = s*32 + g*8 + j
    short8 bfr[4][2];
    #pragma unroll
    for (int tt = 0; tt < 4; tt++) {
        int o = tt*16 + ncol;
        #pragma unroll
        for (int s = 0; s < 2; s++) {
            short8 bb;
            #pragma unroll
            for (int j = 0; j < 8; j++) {
                int c = s*32 + g*8 + j;
                bb[j] = f2bf_s(f2w[(size_t)o*64 + c] * s1s[c]);
            }
            bfr[tt][s] = bb;
        }
    }
    __syncthreads();
    float bias2[4];
    #pragma unroll
    for (int tt = 0; tt < 4; tt++) bias2[tt] = b2s[tt*16 + ncol];
    float ps[4] = {0,0,0,0}, pss[4] = {0,0,0,0};
    int pt0 = blockIdx.x * 16 + w * 4;
    for (int p = 0; p < 4; p++) {
        int pt = pt0 + p, b = pt >> 11, m = pt & (cM - 1);
        if (lane < 48) {
            int c = lane >> 4, k = lane & 15;
            int id = nidx[(size_t)pt * cK + k];
            al4[w][c*16 + k] = sp[((size_t)b*3 + c)*cN + id] - qp[((size_t)b*3 + c)*cM + m];
        }
        WAVE_SYNC();
        // h1raw post-ELU -> bf16 swizzled LDS (row k = 128B)
        #pragma unroll
        for (int k = 0; k < 16; k++) {
            float a0 = al4[w][k], a1 = al4[w][16 + k], a2 = al4[w][32 + k];
            float e = eluf(fb + w0*a0 + w1*a1 + w2*a2);
            int byteoff = (lane*2) ^ ((k & 7) << 4);
            *(uint16_t*)&h1l[w][k*128 + byteoff] = (uint16_t)f2bf_s(e);
        }
        WAVE_SYNC();
        // A-frags: row m = ncol (k of point), c-slice = s*32 + g*8 .. +8
        short8 afr0, afr1;
        {
            int b0 = (g*16) ^ ((ncol & 7) << 4);
            int b1 = (64 + g*16) ^ ((ncol & 7) << 4);
            afr0 = *(const short8*)&h1l[w][ncol*128 + b0];
            afr1 = *(const short8*)&h1l[w][ncol*128 + b1];
        }
        WAVE_SYNC();   // afr consumed before h1l overwritten next p; also orders reads
        #pragma unroll
        for (int tt = 0; tt < 4; tt++) {
            f32x4 acc = {0.f, 0.f, 0.f, 0.f};
            acc = __builtin_amdgcn_mfma_f32_16x16x32_bf16(afr0, bfr[tt][0], acc, 0, 0, 0);
            acc = __builtin_amdgcn_mfma_f32_16x16x32_bf16(afr1, bfr[tt][1], acc, 0, 0, 0);
            // D: col = ncol (o within tile), row = g*4 + r  (k)
            float e0 = eluf(acc[0] + bias2[tt]);
            float e1 = eluf(acc[1] + bias2[tt]);
            float e2 = eluf(acc[2] + bias2[tt]);
            float e3 = eluf(acc[3] + bias2[tt]);
            ps[tt]  += e0+e1+e2+e3;
            pss[tt] += e0*e0+e1*e1+e2*e2+e3*e3;
            int o = tt*16 + ncol, k0 = g*4;
            // h2p layout [pt][o][k/2] matches kI reader
            *(uint2*)(h2p + (size_t)pt*512 + o*8 + (k0 >> 1)) = make_uint2(pk2bf(e0, e1), pk2bf(e2, e3));
        }
    }
    #pragma unroll
    for (int tt = 0; tt < 4; tt++) {
        int o = tt*16 + ncol;
        atomicAdd(&red[o], ps[tt]); atomicAdd(&red[64 + o], pss[tt]);
    }
    __syncthreads();
    if (t < 64) { atomicAdd(&ws[ACC_BN2 + t], red[t]); atomicAdd(&ws[ACC_BN2 + 64 + t], red[64 + t]); }
}

// ---- kI: wave-per-point gather+qf+depthwise. nf channels in registers. ----
__global__ __launch_bounds__(256) void kI(const float* __restrict__ dww,
        const float* __restrict__ f2g, const float* __restrict__ f2be,
        const float* __restrict__ x2g, const float* __restrict__ x2be,
        const int* __restrict__ nidx, float* __restrict__ ws) {
    __shared__ float dws[192 * 17];    // [c][l] pad 17
    __shared__ float xs[4][256];       // per wave x matrix [k*16+l]
    const uint32_t* h2p = (const uint32_t*)(ws + OFF_TST);
    int t = threadIdx.x, lane = t & 63, w = t >> 6;
    for (int l = t; l < 3072; l += 256) dws[(l >> 4)*17 + (l & 15)] = dww[l];
    float sx[4], shx[4];
    #pragma unroll
    for (int i = 0; i < 4; i++) {
        int ch = lane*4 + i;
        float mn = ws[ACC_X2 + ch] * (1.f/16384.f);
        float vr = ws[ACC_X2 + 256 + ch] * (1.f/16384.f) - mn*mn;
        float s = x2g[ch] * rsqrtf(vr + cEPS);
        sx[i] = s; shx[i] = x2be[ch] - mn*s;
    }
    float s2, sh2;
    {
        float mn = ws[ACC_BN2 + lane] * (1.f/262144.f);
        float vr = ws[ACC_BN2 + 64 + lane] * (1.f/262144.f) - mn*mn;
        s2 = f2g[lane] * rsqrtf(vr + cEPS);
        sh2 = f2be[lane] - mn*s2;
    }
    __syncthreads();
    int pt0 = blockIdx.x * 8 + w * 2;
    for (int p = 0; p < 2; p++) {
        int pt = pt0 + p, b = pt >> 11;
        const int4* ip = (const int4*)(nidx + (size_t)pt * cK);
        int4 iA = ip[0], iB = ip[1], iC2 = ip[2], iD = ip[3];
        int idxv[16] = {iA.x, iA.y, iA.z, iA.w, iB.x, iB.y, iB.z, iB.w,
                        iC2.x, iC2.y, iC2.z, iC2.w, iD.x, iD.y, iD.z, iD.w};
        // gather s_feats rows: channels lane, lane+64 in regs
        float nfa[16], nfb[16];
        #pragma unroll
        for (int k = 0; k < 16; k++) {
            const float* rp = ws + OFF_SFT + ((size_t)b*cN + idxv[k]) * cC;
            nfa[k] = rp[lane];
            nfb[k] = rp[lane + 64];
        }
        // h2 (third channel block) with BN2 affine -> regs (packed bf16 pairs)
        float nfh[16];
        {
            const uint4* srcq = (const uint4*)(h2p + (size_t)pt*512 + lane*8);
            uint4 ha = srcq[0], hbq = srcq[1];
            nfh[0]  = s2*bf_lo(ha.x)  + sh2; nfh[1]  = s2*bf_hi(ha.x)  + sh2;
            nfh[2]  = s2*bf_lo(ha.y)  + sh2; nfh[3]  = s2*bf_hi(ha.y)  + sh2;
            nfh[4]  = s2*bf_lo(ha.z)  + sh2; nfh[5]  = s2*bf_hi(ha.z)  + sh2;
            nfh[6]  = s2*bf_lo(ha.w)  + sh2; nfh[7]  = s2*bf_hi(ha.w)  + sh2;
            nfh[8]  = s2*bf_lo(hbq.x) + sh2; nfh[9]  = s2*bf_hi(hbq.x) + sh2;
            nfh[10] = s2*bf_lo(hbq.y) + sh2; nfh[11] = s2*bf_hi(hbq.y) + sh2;
            nfh[12] = s2*bf_lo(hbq.z) + sh2; nfh[13] = s2*bf_hi(hbq.z) + sh2;
            nfh[14] = s2*bf_lo(hbq.w) + sh2; nfh[15] = s2*bf_hi(hbq.w) + sh2;
        }
        // x matrix into per-wave LDS
        {
            float4 v = *(const float4*)&ws[OFF_Y2 + (size_t)pt*256 + lane*4];
            v.x = sx[0]*v.x + shx[0]; v.y = sx[1]*v.y + shx[1];
            v.z = sx[2]*v.z + shx[2]; v.w = sx[3]*v.w + shx[3];
            *(float4*)&xs[w][lane*4] = v;
        }
        WAVE_SYNC();
        // pass 1: channel lane+128 (h2)
        float qc[16];
        #pragma unroll
        for (int l = 0; l < 16; l++) qc[l] = 0.f;
        #pragma unroll
        for (int k = 0; k < 16; k++) {
            float4 x0 = *(const float4*)&xs[w][k*16 + 0];
            float4 x1 = *(const float4*)&xs[w][k*16 + 4];
            float4 x2v = *(const float4*)&xs[w][k*16 + 8];
            float4 x3 = *(const float4*)&xs[w][k*16 + 12];
            float nh = nfh[k];
            qc[0] += nh*x0.x; qc[1] += nh*x0.y; qc[2]  += nh*x0.z; qc[3]  += nh*x0.w;
            qc[4] += nh*x1.x; qc[5] += nh*x1.y; qc[6]  += nh*x1.z; qc[7]  += nh*x1.w;
            qc[8] += nh*x2v.x; qc[9] += nh*x2v.y; qc[10] += nh*x2v.z; qc[11] += nh*x2v.w;
            qc[12] += nh*x3.x; qc[13] += nh*x3.y; qc[14] += nh*x3.z; qc[15] += nh*x3.w;
        }
        float dc = 0;
        #pragma unroll
        for (int l = 0; l < 16; l++) dc += qc[l] * dws[(lane + 128)*17 + l];
        // pass 2: channels lane, lane+64 (gathered)
        float qa[16], qb[16];
        #pragma unroll
        for (int l = 0; l < 16; l++) { qa[l] = 0.f; qb[l] = 0.f; }
        #pragma unroll
        for (int k = 0; k < 16; k++) {
            float4 x0 = *(const float4*)&xs[w][k*16 + 0];
            float4 x1 = *(const float4*)&xs[w][k*16 + 4];
            float4 x2v = *(const float4*)&xs[w][k*16 + 8];
            float4 x3 = *(const float4*)&xs[w][k*16 + 12];
            float na = nfa[k], nb = nfb[k];
            qa[0] += na*x0.x; qa[1] += na*x0.y; qa[2]  += na*x0.z; qa[3]  += na*x0.w;
            qa[4] += na*x1.x; qa[5] += na*x1.y; qa[6]  += na*x1.z; qa[7]  += na*x1.w;
            qa[8] += na*x2v.x; qa[9] += na*x2v.y; qa[10] += na*x2v.z; qa[11] += na*x2v.w;
            qa[12] += na*x3.x; qa[13] += na*x3.y; qa[14] += na*x3.z; qa[15] += na*x3.w;
            qb[0] += nb*x0.x; qb[1] += nb*x0.y; qb[2]  += nb*x0.z; qb[3]  += nb*x0.w;
            qb[4] += nb*x1.x; qb[5] += nb*x1.y; qb[6]  += nb*x1.z; qb[7]  += nb*x1.w;
            qb[8] += nb*x2v.x; qb[9] += nb*x2v.y; qb[10] += nb*x2v.z; qb[11] += nb*x2v.w;
            qb[12] += nb*x3.x; qb[13] += nb*x3.y; qb[14] += nb*x3.z; qb[15] += nb*x3.w;
        }
        float da = 0, db = 0;
        #pragma unroll
        for (int l = 0; l < 16; l++) {
            da += qa[l] * dws[lane*17 + l];
            db += qb[l] * dws[(lane + 64)*17 + l];
        }
        float* op = ws + OFF_DW + (size_t)pt * cCH;
        op[lane] = da; op[lane + 64] = db; op[lane + 128] = dc;
        WAVE_SYNC();   // xs reused next p
    }
}

// ---- kJ: [16384x192]x[192x256] GEMM + bias + ELU + final stats ----
__global__ __launch_bounds__(256) void kJ(const float* __restrict__ pww, const float* __restrict__ pwb,
                                          float* __restrict__ ws, float* __restrict__ out) {
    __shared__ float As[16][65];
    __shared__ float Bs[16][65];
    int t = threadIdx.x;
    int tx = t & 15, ty = t >> 4;
    int p0 = blockIdx.x * 64, o0 = blockIdx.y * 64;
    float acc[4][4];
    #pragma unroll
    for (int i = 0; i < 4; i++)
        #pragma unroll
        for (int j = 0; j < 4; j++) acc[i][j] = 0.f;
    int la = t * 4;
    int apl = la >> 4, akl = la & 15;
    for (int kt = 0; kt < 12; kt++) {
        float4 av = *(const float4*)&ws[OFF_DW + (size_t)(p0 + apl)*cCH + kt*16 + akl];
        float4 bv = *(const float4*)&pww[(size_t)(o0 + apl)*cCH + kt*16 + akl];
        As[akl][apl] = av.x; As[akl+1][apl] = av.y; As[akl+2][apl] = av.z; As[akl+3][apl] = av.w;
        Bs[akl][apl] = bv.x; Bs[akl+1][apl] = bv.y; Bs[akl+2][apl] = bv.z; Bs[akl+3][apl] = bv.w;
        __syncthreads();
        #pragma unroll
        for (int kk = 0; kk < 16; kk++) {
            float a0 = As[kk][tx*4], a1 = As[kk][tx*4+1], a2 = As[kk][tx*4+2], a3 = As[kk][tx*4+3];
            float b0 = Bs[kk][ty*4], b1 = Bs[kk][ty*4+1], b2 = Bs[kk][ty*4+2], b3 = Bs[kk][ty*4+3];
            acc[0][0]+=a0*b0; acc[0][1]+=a0*b1; acc[0][2]+=a0*b2; acc[0][3]+=a0*b3;
            acc[1][0]+=a1*b0; acc[1][1]+=a1*b1; acc[1][2]+=a1*b2; acc[1][3]+=a1*b3;
            acc[2][0]+=a2*b0; acc[2][1]+=a2*b1; acc[2][2]+=a2*b2; acc[2][3]+=a2*b3;
            acc[3][0]+=a3*b0; acc[3][1]+=a3*b1; acc[3][2]+=a3*b2; acc[3][3]+=a3*b3;
        }
        __syncthreads();
    }
    int b = p0 >> 11, mb = (p0 & (cM - 1)) + tx*4;
    #pragma unroll
    for (int j = 0; j < 4; j++) {
        int oo = o0 + ty*4 + j;
        float pb = pwb[oo];
        float e0 = eluf(acc[0][j] + pb), e1 = eluf(acc[1][j] + pb);
        float e2 = eluf(acc[2][j] + pb), e3 = eluf(acc[3][j] + pb);
        float sum = e0+e1+e2+e3, ssq = e0*e0+e1*e1+e2*e2+e3*e3;
        #pragma unroll
        for (int off = 1; off < 16; off <<= 1) { sum += __shfl_xor(sum, off); ssq += __shfl_xor(ssq, off); }
        if (tx == 0) { atomicAdd(&ws[ACC_FIN + oo], sum); atomicAdd(&ws[ACC_FIN + 256 + oo], ssq); }
        float4 st = make_float4(e0, e1, e2, e3);
        *(float4*)&out[((size_t)b*cO + oo)*cM + mb] = st;
    }
}

// ---- kK: final BN affine in-place (inline finalize) ----
__global__ __launch_bounds__(256) void kK(float* __restrict__ out, const float* __restrict__ ws,
        const float* __restrict__ sepg, const float* __restrict__ sepbe) {
    int i = blockIdx.x * 256 + threadIdx.x;
    if (i < (cB*cO*cM) / 4) {
        int o = (i >> 9) & 255;
        float mn = ws[ACC_FIN + o] * (1.f/16384.f);
        float vr = ws[ACC_FIN + 256 + o] * (1.f/16384.f) - mn*mn;
        float s = sepg[o] * rsqrtf(vr + cEPS);
        float sh = sepbe[o] - mn*s;
        float4 v = ((float4*)out)[i];
        v.x = s*v.x + sh; v.y = s*v.y + sh; v.z = s*v.z + sh; v.w = s*v.w + sh;
        ((float4*)out)[i] = v;
    }
}

extern "C" void kernel_launch(void* const* d_in, const int* in_sizes, int n_in,
                              void* d_out, int out_size, void* d_ws, size_t ws_size,
                              hipStream_t stream) {
    const float* qp   = (const float*)d_in[0];
    const float* sp   = (const float*)d_in[1];
    const float* sf   = (const float*)d_in[2];
    const float* f1w  = (const float*)d_in[3];
    const float* f1b  = (const float*)d_in[4];
    const float* f1g  = (const float*)d_in[5];
    const float* f1be = (const float*)d_in[6];
    const float* f2w  = (const float*)d_in[7];
    const float* f2b  = (const float*)d_in[8];
    const float* f2g  = (const float*)d_in[9];
    const float* f2be = (const float*)d_in[10];
    const float* stw  = (const float*)d_in[11];
    const float* stb  = (const float*)d_in[12];
    const float* stg  = (const float*)d_in[13];
    const float* stbe = (const float*)d_in[14];
    const float* x1w  = (const float*)d_in[15];
    const float* x1b  = (const float*)d_in[16];
    const float* x1g  = (const float*)d_in[17];
    const float* x1be = (const float*)d_in[18];
    const float* x2w  = (const float*)d_in[19];
    const float* x2b  = (const float*)d_in[20];
    const float* x2g  = (const float*)d_in[21];
    const float* x2be = (const float*)d_in[22];
    const float* dww  = (const float*)d_in[23];
    const float* pww  = (const float*)d_in[24];
    const float* pwb  = (const float*)d_in[25];
    const float* sepg = (const float*)d_in[26];
    const float* sepbe= (const float*)d_in[27];
    const int*   nidx = (const int*)d_in[28];
    float* ws  = (float*)d_ws;
    float* out = (float*)d_out;
    if (ws_size < WS_FLOATS * sizeof(float)) return;

    hipMemsetAsync(d_ws, 0, 2304 * sizeof(float), stream);  // zero stat accumulators
    k_tr<<<dim3(cN/32, cC/32, cB), dim3(32, 8), 0, stream>>>(sf, ws + OFF_SFT);
    kA<<<NPTS/16, 256, 0, stream>>>(qp, sp, f1w, f1b, stw, stb, nidx, ws);
    kE<<<NPTS/16, 256, 0, stream>>>(x1w, x1b, stg, stbe, ws);
    kG<<<NPTS/16, 256, 0, stream>>>(x2w, x2b, x1g, x1be, ws);
    kC<<<NPTS/16, 256, 0, stream>>>(qp, sp, f1w, f1b, f2w, f2b, f1g, f1be, nidx, ws);
    kI<<<NPTS/8,  256, 0, stream>>>(dww, f2g, f2be, x2g, x2be, nidx, ws);
    kJ<<<dim3(NPTS/64, cO/64), 256, 0, stream>>>(pww, pwb, ws, out);
    kK<<<(cB*cO*cM/4 + 255)/256, 256, 0, stream>>>(out, ws, sepg, sepbe);
}